// Round 7
// baseline (78.025 us; speedup 1.0000x reference)
//
#include <hip/hip_runtime.h>
#include <math.h>

#if defined(__clang__)
#pragma float_control(precise, off)
#endif

// ---------------- compile-time coefficient generation ----------------
constexpr double cfact(int n){ double r=1.0; for (int i=2;i<=n;++i) r*=(double)i; return r; }
constexpr double csq(double x){
  if (x<=0.0) return 0.0;
  double g = x<1.0 ? 1.0 : x;
  for (int i=0;i<64;++i) g = 0.5*(g + x/g);
  return g;
}
constexpr double ccg(int j1,int j2,int m1,int m2,int j,int m){
  if (m1+m2 != m) return 0.0;
  int lo = j1-j2; if (lo<0) lo = -lo;
  if (j < lo || j > j1+j2) return 0.0;
  int am1 = m1<0?-m1:m1, am2 = m2<0?-m2:m2, am = m<0?-m:m;
  if (am1>j1 || am2>j2 || am>j) return 0.0;
  double pref = csq((2.0*j+1.0)*cfact(j+j1-j2)*cfact(j-j1+j2)*cfact(j1+j2-j)/cfact(j1+j2+j+1));
  pref = pref * csq(cfact(j+m)*cfact(j-m)*cfact(j1-m1)*cfact(j1+m1)*cfact(j2-m2)*cfact(j2+m2));
  double tot = 0.0;
  for (int k=0; k<=j1+j2-j; ++k){
    int d0=k, d1=j1+j2-j-k, d2=j1-m1-k, d3=j2+m2-k, d4=j-j2+m1+k, d5=j-j1-m2+k;
    if (d0<0||d1<0||d2<0||d3<0||d4<0||d5<0) continue;
    double p = cfact(d0)*cfact(d1)*cfact(d2)*cfact(d3)*cfact(d4)*cfact(d5);
    tot += ((k&1)? -1.0 : 1.0)/p;
  }
  return pref*tot;
}
constexpr double cq(double m, double m1, double m2){
  double ms=m1+m2, md=m1-m2;
  return csq((m+ms)*(m-ms)*(m+md)*(m-md))/(2.0*m);
}

struct ZcTab { float F1[3][2]; float F2[3][3][3]; };
constexpr ZcTab mkZcT(){
  ZcTab t{};
  const int l0l[2]={0,2}; const int l0s[2]={1,1};
  for (int ir=0; ir<3; ++ir){
    int r = ir-1;
    for (int i=0;i<2;++i){
      int l=l0l[i], s=l0s[i];
      t.F1[ir][i] = (float)( csq((2.0*l+1.0)/3.0)*ccg(1,0,r,0,s,r)*ccg(l,s,0,r,1,r) );
    }
  }
  const int l1l[3]={0,2,2}; const int l1s[3]={1,1,2};
  for (int ip=0; ip<3; ++ip) for (int iw=0; iw<3; ++iw){
    int p=ip-1, w=iw-1;
    for (int i=0;i<3;++i){
      int l=l1l[i], s=l1s[i];
      t.F2[ip][iw][i] = (float)( csq((2.0*l+1.0)/3.0)*ccg(1,1,p,-w,s,p-w)*ccg(l,s,0,p-w,1,p-w) );
    }
  }
  return t;
}
struct D2Tab { float F1[5][3][5]; float F2[3]; };
constexpr D2Tab mkD2T(){
  D2Tab t{};
  const int l0l[5]={0,2,2,2,4}; const int l0s[5]={1,1,2,3,3};
  for (int ir=0;ir<5;++ir) for (int jf=0;jf<3;++jf){
    int r=ir-2, f=jf-1;
    for (int i=0;i<5;++i){
      int l=l0l[i], s=l0s[i];
      t.F1[ir][jf][i] = (float)( csq((2.0*l+1.0)/3.0)*ccg(2,1,r,-f,s,r-f)*ccg(l,s,0,r-f,1,r-f) );
    }
  }
  for (int ip=0;ip<3;++ip){
    int p=ip-1;
    t.F2[ip] = (float)( ccg(1,0,p,0,1,p)*ccg(2,1,0,p,2,p) );
  }
  return t;
}
struct D1Tab { float F1[3][3][3]; float F2[3][2]; };
constexpr D1Tab mkD1T(){
  D1Tab t{};
  const int l0l[3]={0,2,2}; const int l0s[3]={1,1,2};
  for (int ir=0;ir<3;++ir) for (int ie=0;ie<3;++ie){
    int r=ir-1, e=ie-1;
    for (int i=0;i<3;++i){
      int l=l0l[i], s=l0s[i];
      t.F1[ir][ie][i] = (float)( csq((2.0*l+1.0)/3.0)*ccg(1,1,r,-e,s,r-e)*ccg(l,s,0,r-e,1,r-e) );
    }
  }
  const int l1l[2]={0,2}; const int l1s[2]={1,1};
  for (int iw=0;iw<3;++iw){
    int w=iw-1;
    for (int i=0;i<2;++i){
      int l=l1l[i], s=l1s[i];
      t.F2[iw][i] = (float)( csq((2.0*l+1.0)/3.0)*ccg(0,1,w,0,s,w)*ccg(l,s,0,w,1,w) );
    }
  }
  return t;
}
constexpr ZcTab ZT  = mkZcT();
constexpr D2Tab D2T = mkD2T();
constexpr D1Tab D1T = mkD1T();

constexpr double ECd=4.59925, MBd=2.01026, MCd=0.13957061, MDd=2.00685;
constexpr float ZC_Q0RT = (float)cq(ECd, MCd, 4.026);
constexpr float ZC_Q0ND = (float)cq(4.026, MBd, MCd);
constexpr float ZC_Q0BW = (float)cq(4.026, MBd, MDd);
constexpr float D2_Q0RT = (float)cq(ECd, MDd, 2.4607);
constexpr float D2_Q0ND = (float)cq(2.4607, MBd, MCd);
constexpr float D1_Q0RT = (float)cq(ECd, MBd, 2.427);
constexpr float D1_Q0ND = (float)cq(2.427, MCd, MDd);

#define ECOMf 4.59925f
#define M0Bf  2.01026f
#define M0Cf  0.13957061f
#define M0Df  2.00685f

// ---------------- device helpers (NO libcalls anywhere) ----------------
struct cf { float x, y; };
__device__ __forceinline__ cf cmul(cf a, cf b){ return {a.x*b.x - a.y*b.y, a.x*b.y + a.y*b.x}; }
__device__ __forceinline__ cf cmulr(cf a, float s){ return {a.x*s, a.y*s}; }
__device__ __forceinline__ cf cadd(cf a, cf b){ return {a.x+b.x, a.y+b.y}; }
__device__ __forceinline__ cf cconj(cf a){ return {a.x, -a.y}; }

__device__ __forceinline__ float hsqrt(float x){ return __builtin_amdgcn_sqrtf(x); }

// packed bf16 pair (x lo, y hi), round-to-nearest-even
__device__ __forceinline__ unsigned bfpack(cf v){
  unsigned ux = __float_as_uint(v.x);
  unsigned uy = __float_as_uint(v.y);
  ux += 0x7FFFu + ((ux>>16)&1u);
  uy += 0x7FFFu + ((uy>>16)&1u);
  return (ux>>16) | (uy & 0xFFFF0000u);
}
__device__ __forceinline__ cf bfunpk(unsigned u){
  return { __uint_as_float(u<<16), __uint_as_float(u & 0xFFFF0000u) };
}

__device__ __forceinline__ float getqf(float m, float m1, float m2){
  float ms = m1+m2, md = m1-m2;
  return hsqrt((m+ms)*(m-ms)*(m+md)*(m-md))/(2.f*m);
}
__device__ __forceinline__ float barrier2f(float z){ return 9.f + (3.f+z)*z; }
__device__ __forceinline__ float barrier4f(float z){ return z*(z*(z*(z+10.f)+135.f)+1575.f)+11025.f; }
__device__ __forceinline__ float rad2f(float q, float q0){
  float z = 9.f*q*q, z0 = 9.f*q0*q0;
  return q*q*hsqrt(barrier2f(z0)/barrier2f(z));
}
__device__ __forceinline__ float rad4f(float q, float q0){
  float z = 9.f*q*q, z0 = 9.f*q0*q0;
  float q2 = q*q;
  return q2*q2*hsqrt(barrier4f(z0)/barrier4f(z));
}
// exp(-i a) via HW v_sin/v_cos (input in revolutions; |a|<=pi -> |rev|<=0.5, in range)
__device__ __forceinline__ cf epha(float a){
  const float r = a * 0.15915494309189535f;
  float c = __builtin_amdgcn_cosf(r);
  float s = __builtin_amdgcn_sinf(r);
  return {c, -s};
}

struct Ptrs { const float* p[28]; };

#define SCHED_WALL() __builtin_amdgcn_sched_barrier(0)

// ---------------- macro machinery (all indices literal -> pure SSA) ----------------
#define EF_LIST(X) X(0,0) X(0,1) X(0,2) X(1,0) X(1,1) X(1,2) X(2,0) X(2,1) X(2,2)

// e^{-i m phi} by index M = m+1
#define PH_0(E) cconj(E)
#define PH_1(E) cf{1.f,0.f}
#define PH_2(E) (E)
#define PH_(M,E) PH_##M(E)
#define PH(M,E)  PH_(M,E)

// d^1 entries by literal [R][C], prefix P gives scalars P##A2,P##AB,P##B2,P##CC
#define D1_00(P) (P##A2)
#define D1_01(P) (P##AB)
#define D1_02(P) (P##B2)
#define D1_10(P) (-(P##AB))
#define D1_11(P) (P##CC)
#define D1_12(P) (P##AB)
#define D1_20(P) (P##B2)
#define D1_21(P) (-(P##AB))
#define D1_22(P) (P##A2)
#define D1E_(R,C,P) D1_##R##C(P)
#define D1E(R,C,P)  D1E_(R,C,P)

#define MK_D1S(P, CB) \
  float P##A2 = 0.5f*(1.f+(CB)); \
  float P##B2 = 0.5f*(1.f-(CB)); \
  float P##AB = 1.4142135623730951f*hsqrt(fmaxf(0.f, P##A2*P##B2)); \
  float P##CC = P##A2 - P##B2;

// d^2 entries by literal [R][C] (cols 1..3 only), scalars w_*
#define D2_0_1 (w_a3)
#define D2_0_2 (w_u6)
#define D2_0_3 (w_b3)
#define D2_1_1 (w_c1)
#define D2_1_2 (w_t6)
#define D2_1_3 (w_c2)
#define D2_2_1 (-w_t6)
#define D2_2_2 (w_c0)
#define D2_2_3 (w_t6)
#define D2_3_1 (w_c2)
#define D2_3_2 (-w_t6)
#define D2_3_3 (w_c1)
#define D2_4_1 (-w_b3)
#define D2_4_2 (w_u6)
#define D2_4_3 (-w_a3)
#define D2E_(R,C) D2_##R##_##C
#define D2E(R,C)  D2E_(R,C)

// chain-local amplitude accumulators: A{a}_{e}{f}
#define DECL_A(E,F) cf A0_##E##F = {0.f,0.f}; cf A1_##E##F = {0.f,0.f};
// LDS merge macros (per-thread private slots, packed bf16 -> no syncs, 18.4 KB/block)
#define STORE1(E,F) accL[(E)*3+(F)][tid] = bfpack(A0_##E##F); \
                    accL[18+(E)*3+(F)][tid] = bfpack(A1_##E##F);
#define MERGE2(E,F) accL[(E)*3+(F)][tid] = bfpack(cadd(bfunpk(accL[(E)*3+(F)][tid]), A0_##E##F)); \
                    accL[18+(E)*3+(F)][tid] = bfpack(cadd(bfunpk(accL[18+(E)*3+(F)][tid]), A1_##E##F));
#define FIN3(E,F) { cf s0 = cadd(bfunpk(accL[(E)*3+(F)][tid]), A0_##E##F); psum += s0.x*s0.x + s0.y*s0.y; \
                    cf s1 = cadd(bfunpk(accL[18+(E)*3+(F)][tid]), A1_##E##F); psum += s1.x*s1.x + s1.y*s1.y; }

// ---- Zc chain macros ----
#define MK_DD(W,F) cf DD_##W##F = cmulr(cmul(PH(W,eDa), PH(F,eDg)), D1E(W,F,v));
#define MK_DB(P,E) cf DB_##P##E = cmulr(cmul(PH(P,eBa), PH(E,eBg)), D1E(P,E,b));
#define MK_F2(P,W) cf F2_##P##W = cadd(cmulr(g2, ZT.F2[P][W][0]), \
                      cadd(cmulr(g3r, ZT.F2[P][W][1]), cmulr(g4r, ZT.F2[P][W][2])));

#define ZC_ACC_E(P,E) { \
  cf c0 = cmul(za0, DB_##P##E); \
  cf c1 = cmul(za1, DB_##P##E); \
  A0_##E##0 = cadd(A0_##E##0, cmul(c0, G0)); A1_##E##0 = cadd(A1_##E##0, cmul(c1, G0)); \
  A0_##E##1 = cadd(A0_##E##1, cmul(c0, G1)); A1_##E##1 = cadd(A1_##E##1, cmul(c1, G1)); \
  A0_##E##2 = cadd(A0_##E##2, cmul(c0, G2)); A1_##E##2 = cadd(A1_##E##2, cmul(c1, G2)); }
#define ZC_ACC(P) ZC_ACC_E(P,0) ZC_ACC_E(P,1) ZC_ACC_E(P,2)

#define ZC_P0(R) { \
  cf t0 = cmulr(F2_00, D1E(R,1,r)); \
  cf t1 = cmulr(F2_01, D1E(R,0,r)); \
  cf G0 = cadd(cmul(t0, DD_00), cmul(t1, DD_10)); \
  cf G1 = cadd(cmul(t0, DD_01), cmul(t1, DD_11)); \
  cf G2 = cadd(cmul(t0, DD_02), cmul(t1, DD_12)); \
  ZC_ACC(0) }
#define ZC_P1(R) { \
  cf t0 = cmulr(F2_10, D1E(R,2,r)); \
  cf t1 = cmulr(F2_11, D1E(R,1,r)); \
  cf t2 = cmulr(F2_12, D1E(R,0,r)); \
  cf G0 = cadd(cadd(cmul(t0, DD_00), cmul(t1, DD_10)), cmul(t2, DD_20)); \
  cf G1 = cadd(cadd(cmul(t0, DD_01), cmul(t1, DD_11)), cmul(t2, DD_21)); \
  cf G2 = cadd(cadd(cmul(t0, DD_02), cmul(t1, DD_12)), cmul(t2, DD_22)); \
  ZC_ACC(1) }
#define ZC_P2(R) { \
  cf t1 = cmulr(F2_21, D1E(R,2,r)); \
  cf t2 = cmulr(F2_22, D1E(R,1,r)); \
  cf G0 = cadd(cmul(t1, DD_10), cmul(t2, DD_20)); \
  cf G1 = cadd(cmul(t1, DD_11), cmul(t2, DD_21)); \
  cf G2 = cadd(cmul(t1, DD_12), cmul(t2, DD_22)); \
  ZC_ACC(2) }

#define ZC_R(R) { \
  cf F1c = cadd(cmulr(g0, ZT.F1[R][0]), cmulr(g1r, ZT.F1[R][1])); \
  cf Zr  = cmul(F1c, PH(R,eR)); \
  cf za0 = cmulr(cmul(Zr, Ua0), D1E(0,R,a)); \
  cf za1 = cmulr(cmul(Zr, Ua1), D1E(2,R,a)); \
  ZC_P0(R) ZC_P1(R) ZC_P2(R) }

// ---- D2 chain macros ----
#define MK_DBG(P,E) cf dBg_##P##E = cmulr(PH(E,eBg), D1E(P,E,b));
#define D2_W(R) \
  cf t0 = cmulr(F2p_0, D2E(R,1)); \
  cf t1 = cmulr(F2p_1, D2E(R,2)); \
  cf t2 = cmulr(F2p_2, D2E(R,3)); \
  cf W0 = cadd(cadd(cmul(t0,dBg_00), cmul(t1,dBg_10)), cmul(t2,dBg_20)); \
  cf W1 = cadd(cadd(cmul(t0,dBg_01), cmul(t1,dBg_11)), cmul(t2,dBg_21)); \
  cf W2 = cadd(cadd(cmul(t0,dBg_02), cmul(t1,dBg_12)), cmul(t2,dBg_22));
#define D2F(R,F,K1) { \
  cf zf = cmulr(g5, D2T.F1[R][F][0]); \
  zf = cadd(zf, cmulr(g6r, D2T.F1[R][F][1])); \
  zf = cadd(zf, cmulr(g7r, D2T.F1[R][F][2])); \
  zf = cadd(zf, cmulr(g8r, D2T.F1[R][F][3])); \
  zf = cadd(zf, cmulr(g9r, D2T.F1[R][F][4])); \
  cf z0 = cmulr(cmul(zf, Zb0), D1E(0,K1,a)); \
  cf z1 = cmulr(cmul(zf, Zb1), D1E(2,K1,a)); \
  A0_0##F = cadd(A0_0##F, cmul(z0, W0)); A1_0##F = cadd(A1_0##F, cmul(z1, W0)); \
  A0_1##F = cadd(A0_1##F, cmul(z0, W1)); A1_1##F = cadd(A1_1##F, cmul(z1, W1)); \
  A0_2##F = cadd(A0_2##F, cmul(z0, W2)); A1_2##F = cadd(A1_2##F, cmul(z1, W2)); }

// ---- D1 chain macros ----
#define MK_DDG(W,F) cf dDg_##W##F = cmulr(PH(F,eDg), D1E(W,F,v));
#define D1_G(R) \
  cf t0 = cmulr(F2p_0, D1E(R,0,r)); \
  cf t1 = cmulr(F2p_1, D1E(R,1,r)); \
  cf t2 = cmulr(F2p_2, D1E(R,2,r)); \
  cf G0 = cadd(cadd(cmul(t0,dDg_00), cmul(t1,dDg_10)), cmul(t2,dDg_20)); \
  cf G1 = cadd(cadd(cmul(t0,dDg_01), cmul(t1,dDg_11)), cmul(t2,dDg_21)); \
  cf G2 = cadd(cadd(cmul(t0,dDg_02), cmul(t1,dDg_12)), cmul(t2,dDg_22));
#define D1F(R,E,K1) { \
  cf ze = cmulr(g11, D1T.F1[R][E][0]); \
  ze = cadd(ze, cmulr(g12r, D1T.F1[R][E][1])); \
  ze = cadd(ze, cmulr(g13r, D1T.F1[R][E][2])); \
  cf z0 = cmulr(cmul(ze, Zb0), D1E(0,K1,a)); \
  cf z1 = cmulr(cmul(ze, Zb1), D1E(2,K1,a)); \
  A0_##E##0 = cadd(A0_##E##0, cmul(z0, G0)); A1_##E##0 = cadd(A1_##E##0, cmul(z1, G0)); \
  A0_##E##1 = cadd(A0_##E##1, cmul(z0, G1)); A1_##E##1 = cadd(A1_##E##1, cmul(z1, G1)); \
  A0_##E##2 = cadd(A0_##E##2, cmul(z0, G2)); A1_##E##2 = cadd(A1_##E##2, cmul(z1, G2)); }

// ---------------- kernel ----------------
__global__ __launch_bounds__(128, 4) void amp_kernel(Ptrs P, float* __restrict__ out, int N){
  const int tid = threadIdx.x;
  const int gid = blockIdx.x * blockDim.x + tid;
  __shared__ unsigned accL[36][128];   // per-thread private cross-chain accumulator, packed bf16 (18.4 KB)
  float psum = 0.f;
  if (gid < N) {
    const int n = gid;
    const float* __restrict__ gls = P.p[27];

    //=========== Zc_4025 (BD chain, Jr=1) ===========
    {
      EF_LIST(DECL_A)
      const float m    = P.p[8][n];
      const float phiA = P.p[9][n];
      const float cosA = P.p[10][n];
      const float phiR = P.p[11][n];
      const float cosR = P.p[12][n];
      const float aBv  = P.p[13][n];
      const float cbB  = P.p[14][n];
      const float gBv  = P.p[15][n];
      const float aDv  = P.p[16][n];
      const float cbD  = P.p[17][n];
      const float gDv  = P.p[18][n];

      cf g0={gls[0],gls[1]}, g1={gls[2],gls[3]}, g2={gls[4],gls[5]},
         g3={gls[6],gls[7]}, g4={gls[8],gls[9]};

      float q_rt = getqf(ECOMf, M0Cf, m);
      float q_nd = getqf(m, M0Bf, M0Df);
      float r2rt = rad2f(q_rt, ZC_Q0RT);
      float r2nd = rad2f(q_nd, ZC_Q0ND);

      float width = 0.025f * (q_nd * (1.f/ZC_Q0BW)) * (4.026f / m);
      float dre = m*m - 4.026f*4.026f, dim_ = 4.026f*width;
      float inv = 1.f/(dre*dre + dim_*dim_);
      cf bw = { dre*inv, -dim_*inv };

      cf eA = epha(phiA); cf eAc = cconj(eA);
      cf eR = epha(phiR), eBa = epha(aBv), eBg = epha(gBv), eDa = epha(aDv), eDg = epha(gDv);
      cf Ua0 = cmul(bw, eAc);
      cf Ua1 = cmul(bw, eA);

      MK_D1S(a, cosA)
      MK_D1S(r, cosR)
      MK_D1S(b, cbB)
      MK_D1S(v, cbD)

      cf g1r = cmulr(g1, r2rt);
      cf g3r = cmulr(g3, r2nd);
      cf g4r = cmulr(g4, r2nd);

      EF_LIST(MK_DD)
      EF_LIST(MK_DB)
      EF_LIST(MK_F2)
      ZC_R(0) ZC_R(1) ZC_R(2)

      EF_LIST(STORE1)
    }

    SCHED_WALL();

    //=========== D2_2460 (BC chain, Jr=2) ===========
    {
      EF_LIST(DECL_A)
      const float m    = P.p[0][n];
      const float phiA = P.p[1][n];
      const float cosA = P.p[2][n];
      const float phiR = P.p[3][n];
      const float cosR = P.p[4][n];
      const float aBv  = P.p[5][n];
      const float cbB  = P.p[6][n];
      const float gBv  = P.p[7][n];

      cf g5={gls[10],gls[11]}, g6={gls[12],gls[13]}, g7={gls[14],gls[15]},
         g8={gls[16],gls[17]}, g9={gls[18],gls[19]}, g10={gls[20],gls[21]};

      float q_rt = getqf(ECOMf, M0Df, m);
      float q_nd = getqf(m, M0Bf, M0Cf);
      float r2rt = rad2f(q_rt, D2_Q0RT);
      float r4rt = rad4f(q_rt, D2_Q0RT);
      float r2nd = rad2f(q_nd, D2_Q0ND);

      float z = 9.f*q_nd*q_nd;
      float bpr2 = barrier2f(9.f*D2_Q0ND*D2_Q0ND)/barrier2f(z);
      float qr = q_nd*(1.f/D2_Q0ND);
      float width = 0.0475f * qr*qr*qr*qr*qr * (2.4607f/m) * bpr2;
      float dre = m*m - 2.4607f*2.4607f, dim_ = 2.4607f*width;
      float inv = 1.f/(dre*dre + dim_*dim_);
      cf bw = { dre*inv, -dim_*inv };

      cf eA = epha(phiA); cf eAc = cconj(eA);
      cf eR = epha(phiR), eBa = epha(aBv), eBg = epha(gBv);
      cf eR2 = cmul(eR, eR);

      MK_D1S(a, cosA)
      MK_D1S(b, cbB)

      float w_A2 = 0.5f*(1.f+cosR);
      float w_B2 = 0.5f*(1.f-cosR);
      float w_u  = w_A2*w_B2;
      float w_AB = hsqrt(fmaxf(0.f, w_u));
      const float R6 = 2.449489742783178f;
      float w_a3 = 2.f*w_A2*w_AB, w_b3 = 2.f*w_B2*w_AB;
      float w_t6 = R6*w_AB*(w_A2-w_B2), w_u6 = R6*w_u;
      float w_c1 = w_A2*w_A2 - 3.f*w_u;
      float w_c2 = 3.f*w_u - w_B2*w_B2;
      float w_c0 = w_A2*w_A2 - 4.f*w_u + w_B2*w_B2;

      cf g6r = cmulr(g6, r2rt), g7r = cmulr(g7, r2rt), g8r = cmulr(g8, r2rt);
      cf g9r = cmulr(g9, r4rt);
      cf g10r = cmulr(g10, r2nd);

      cf F2p_0 = cmul(cmulr(g10r, D2T.F2[0]), PH(0,eBa));
      cf F2p_1 = cmul(cmulr(g10r, D2T.F2[1]), PH(1,eBa));
      cf F2p_2 = cmul(cmulr(g10r, D2T.F2[2]), PH(2,eBa));

      EF_LIST(MK_DBG)

      { cf zb = cmul(bw, cconj(eR2)); cf Zb0 = cmul(zb, eAc), Zb1 = cmul(zb, eA);
        D2_W(0) D2F(0,0,0) }
      { cf zb = cmul(bw, cconj(eR));  cf Zb0 = cmul(zb, eAc), Zb1 = cmul(zb, eA);
        D2_W(1) D2F(1,0,1) D2F(1,1,0) }
      { cf zb = bw;                   cf Zb0 = cmul(zb, eAc), Zb1 = cmul(zb, eA);
        D2_W(2) D2F(2,0,2) D2F(2,1,1) D2F(2,2,0) }
      { cf zb = cmul(bw, eR);         cf Zb0 = cmul(zb, eAc), Zb1 = cmul(zb, eA);
        D2_W(3) D2F(3,1,2) D2F(3,2,1) }
      { cf zb = cmul(bw, eR2);        cf Zb0 = cmul(zb, eAc), Zb1 = cmul(zb, eA);
        D2_W(4) D2F(4,2,2) }

      EF_LIST(MERGE2)
    }

    SCHED_WALL();

    //=========== D1_2430 (CD chain, Jr=1) ===========
    {
      EF_LIST(DECL_A)
      const float m    = P.p[19][n];
      const float phiA = P.p[20][n];
      const float cosA = P.p[21][n];
      const float phiR = P.p[22][n];
      const float cosR = P.p[23][n];
      const float aDv  = P.p[24][n];
      const float cbD  = P.p[25][n];
      const float gDv  = P.p[26][n];

      cf g11={gls[22],gls[23]}, g12={gls[24],gls[25]}, g13={gls[26],gls[27]},
         g14={gls[28],gls[29]}, g15={gls[30],gls[31]};

      float q_rt = getqf(ECOMf, M0Bf, m);
      float q_nd = getqf(m, M0Cf, M0Df);
      float r2rt = rad2f(q_rt, D1_Q0RT);
      float r2nd = rad2f(q_nd, D1_Q0ND);

      float width = 0.384f * (q_nd*(1.f/D1_Q0ND)) * (2.427f/m);
      float dre = m*m - 2.427f*2.427f, dim_ = 2.427f*width;
      float inv = 1.f/(dre*dre + dim_*dim_);
      cf bw = { dre*inv, -dim_*inv };

      cf eA = epha(phiA); cf eAc = cconj(eA);
      cf eR = epha(phiR), eDa = epha(aDv), eDg = epha(gDv);

      MK_D1S(a, cosA)
      MK_D1S(r, cosR)
      MK_D1S(v, cbD)

      cf g12r = cmulr(g12, r2rt), g13r = cmulr(g13, r2rt);
      cf g15r = cmulr(g15, r2nd);

      cf F2p_0 = cmul(cadd(cmulr(g14, D1T.F2[0][0]), cmulr(g15r, D1T.F2[0][1])), PH(0,eDa));
      cf F2p_1 = cmul(cadd(cmulr(g14, D1T.F2[1][0]), cmulr(g15r, D1T.F2[1][1])), PH(1,eDa));
      cf F2p_2 = cmul(cadd(cmulr(g14, D1T.F2[2][0]), cmulr(g15r, D1T.F2[2][1])), PH(2,eDa));

      EF_LIST(MK_DDG)

      { cf zb = cmul(bw, cconj(eR)); cf Zb0 = cmul(zb, eAc), Zb1 = cmul(zb, eA);
        D1_G(0) D1F(0,0,1) D1F(0,1,0) }
      { cf zb = bw;                  cf Zb0 = cmul(zb, eAc), Zb1 = cmul(zb, eA);
        D1_G(1) D1F(1,0,2) D1F(1,1,1) D1F(1,2,0) }
      { cf zb = cmul(bw, eR);        cf Zb0 = cmul(zb, eAc), Zb1 = cmul(zb, eA);
        D1_G(2) D1F(2,1,2) D1F(2,2,1) }

      EF_LIST(FIN3)
    }
  }

  // wave + block reduction, one atomic per block (128 threads = 2 waves)
  #pragma unroll
  for (int off=32; off>0; off>>=1) psum += __shfl_down(psum, off, 64);
  __shared__ float red[2];
  int lane = threadIdx.x & 63, wid = threadIdx.x >> 6;
  if (lane == 0) red[wid] = psum;
  __syncthreads();
  if (threadIdx.x == 0) atomicAdd(out, red[0]+red[1]);
}

// ---------------- launch ----------------
extern "C" void kernel_launch(void* const* d_in, const int* in_sizes, int n_in,
                              void* d_out, int out_size, void* d_ws, size_t ws_size,
                              hipStream_t stream){
  (void)n_in; (void)d_ws; (void)ws_size;
  Ptrs P;
  for (int i=0; i<28; ++i) P.p[i] = (const float*)d_in[i];
  int N = in_sizes[0];
  hipMemsetAsync(d_out, 0, (size_t)out_size * sizeof(float), stream);
  int grid = (N + 127) / 128;
  amp_kernel<<<grid, 128, 0, stream>>>(P, (float*)d_out, N);
}

// Round 8
// 72.160 us; speedup vs baseline: 1.0813x; 1.0813x over previous
//
#include <hip/hip_runtime.h>
#include <math.h>

#if defined(__clang__)
#pragma float_control(precise, off)
#endif

// ---------------- compile-time coefficient generation ----------------
constexpr double cfact(int n){ double r=1.0; for (int i=2;i<=n;++i) r*=(double)i; return r; }
constexpr double csq(double x){
  if (x<=0.0) return 0.0;
  double g = x<1.0 ? 1.0 : x;
  for (int i=0;i<64;++i) g = 0.5*(g + x/g);
  return g;
}
constexpr double ccg(int j1,int j2,int m1,int m2,int j,int m){
  if (m1+m2 != m) return 0.0;
  int lo = j1-j2; if (lo<0) lo = -lo;
  if (j < lo || j > j1+j2) return 0.0;
  int am1 = m1<0?-m1:m1, am2 = m2<0?-m2:m2, am = m<0?-m:m;
  if (am1>j1 || am2>j2 || am>j) return 0.0;
  double pref = csq((2.0*j+1.0)*cfact(j+j1-j2)*cfact(j-j1+j2)*cfact(j1+j2-j)/cfact(j1+j2+j+1));
  pref = pref * csq(cfact(j+m)*cfact(j-m)*cfact(j1-m1)*cfact(j1+m1)*cfact(j2-m2)*cfact(j2+m2));
  double tot = 0.0;
  for (int k=0; k<=j1+j2-j; ++k){
    int d0=k, d1=j1+j2-j-k, d2=j1-m1-k, d3=j2+m2-k, d4=j-j2+m1+k, d5=j-j1-m2+k;
    if (d0<0||d1<0||d2<0||d3<0||d4<0||d5<0) continue;
    double p = cfact(d0)*cfact(d1)*cfact(d2)*cfact(d3)*cfact(d4)*cfact(d5);
    tot += ((k&1)? -1.0 : 1.0)/p;
  }
  return pref*tot;
}
constexpr double cq(double m, double m1, double m2){
  double ms=m1+m2, md=m1-m2;
  return csq((m+ms)*(m-ms)*(m+md)*(m-md))/(2.0*m);
}

struct ZcTab { float F1[3][2]; float F2[3][3][3]; };
constexpr ZcTab mkZcT(){
  ZcTab t{};
  const int l0l[2]={0,2}; const int l0s[2]={1,1};
  for (int ir=0; ir<3; ++ir){
    int r = ir-1;
    for (int i=0;i<2;++i){
      int l=l0l[i], s=l0s[i];
      t.F1[ir][i] = (float)( csq((2.0*l+1.0)/3.0)*ccg(1,0,r,0,s,r)*ccg(l,s,0,r,1,r) );
    }
  }
  const int l1l[3]={0,2,2}; const int l1s[3]={1,1,2};
  for (int ip=0; ip<3; ++ip) for (int iw=0; iw<3; ++iw){
    int p=ip-1, w=iw-1;
    for (int i=0;i<3;++i){
      int l=l1l[i], s=l1s[i];
      t.F2[ip][iw][i] = (float)( csq((2.0*l+1.0)/3.0)*ccg(1,1,p,-w,s,p-w)*ccg(l,s,0,p-w,1,p-w) );
    }
  }
  return t;
}
struct D2Tab { float F1[5][3][5]; float F2[3]; };
constexpr D2Tab mkD2T(){
  D2Tab t{};
  const int l0l[5]={0,2,2,2,4}; const int l0s[5]={1,1,2,3,3};
  for (int ir=0;ir<5;++ir) for (int jf=0;jf<3;++jf){
    int r=ir-2, f=jf-1;
    for (int i=0;i<5;++i){
      int l=l0l[i], s=l0s[i];
      t.F1[ir][jf][i] = (float)( csq((2.0*l+1.0)/3.0)*ccg(2,1,r,-f,s,r-f)*ccg(l,s,0,r-f,1,r-f) );
    }
  }
  for (int ip=0;ip<3;++ip){
    int p=ip-1;
    t.F2[ip] = (float)( ccg(1,0,p,0,1,p)*ccg(2,1,0,p,2,p) );
  }
  return t;
}
struct D1Tab { float F1[3][3][3]; float F2[3][2]; };
constexpr D1Tab mkD1T(){
  D1Tab t{};
  const int l0l[3]={0,2,2}; const int l0s[3]={1,1,2};
  for (int ir=0;ir<3;++ir) for (int ie=0;ie<3;++ie){
    int r=ir-1, e=ie-1;
    for (int i=0;i<3;++i){
      int l=l0l[i], s=l0s[i];
      t.F1[ir][ie][i] = (float)( csq((2.0*l+1.0)/3.0)*ccg(1,1,r,-e,s,r-e)*ccg(l,s,0,r-e,1,r-e) );
    }
  }
  const int l1l[2]={0,2}; const int l1s[2]={1,1};
  for (int iw=0;iw<3;++iw){
    int w=iw-1;
    for (int i=0;i<2;++i){
      int l=l1l[i], s=l1s[i];
      t.F2[iw][i] = (float)( csq((2.0*l+1.0)/3.0)*ccg(0,1,w,0,s,w)*ccg(l,s,0,w,1,w) );
    }
  }
  return t;
}
constexpr ZcTab ZT  = mkZcT();
constexpr D2Tab D2T = mkD2T();
constexpr D1Tab D1T = mkD1T();

constexpr double ECd=4.59925, MBd=2.01026, MCd=0.13957061, MDd=2.00685;
constexpr float ZC_Q0RT = (float)cq(ECd, MCd, 4.026);
constexpr float ZC_Q0ND = (float)cq(4.026, MBd, MCd);
constexpr float ZC_Q0BW = (float)cq(4.026, MBd, MDd);
constexpr float D2_Q0RT = (float)cq(ECd, MDd, 2.4607);
constexpr float D2_Q0ND = (float)cq(2.4607, MBd, MCd);
constexpr float D1_Q0RT = (float)cq(ECd, MBd, 2.427);
constexpr float D1_Q0ND = (float)cq(2.427, MCd, MDd);

#define ECOMf 4.59925f
#define M0Bf  2.01026f
#define M0Cf  0.13957061f
#define M0Df  2.00685f

// ---------------- complex as packed float2 (targets v_pk_*_f32 VOP3P) ----------------
typedef float cf __attribute__((ext_vector_type(2)));
__device__ __forceinline__ cf mkcf(float x, float y){ cf r; r.x = x; r.y = y; return r; }
__device__ __forceinline__ cf cadd(cf a, cf b){ return a + b; }
__device__ __forceinline__ cf cmulr(cf a, float s){ return a * s; }
__device__ __forceinline__ cf cconj(cf a){ return mkcf(a.x, -a.y); }
// (ax*bx - ay*by, ax*by + ay*bx) = a.xx*b + a.yy*(-b.y, b.x)  -> 2x v_pk_fma_f32
__device__ __forceinline__ cf cmul(cf a, cf b){
  return a.xx * b + a.yy * mkcf(-b.y, b.x);
}

__device__ __forceinline__ float hsqrt(float x){ return __builtin_amdgcn_sqrtf(x); }

__device__ __forceinline__ float getqf(float m, float m1, float m2){
  float ms = m1+m2, md = m1-m2;
  return hsqrt((m+ms)*(m-ms)*(m+md)*(m-md))/(2.f*m);
}
__device__ __forceinline__ float barrier2f(float z){ return 9.f + (3.f+z)*z; }
__device__ __forceinline__ float barrier4f(float z){ return z*(z*(z*(z+10.f)+135.f)+1575.f)+11025.f; }
__device__ __forceinline__ float rad2f(float q, float q0){
  float z = 9.f*q*q, z0 = 9.f*q0*q0;
  return q*q*hsqrt(barrier2f(z0)/barrier2f(z));
}
__device__ __forceinline__ float rad4f(float q, float q0){
  float z = 9.f*q*q, z0 = 9.f*q0*q0;
  float q2 = q*q;
  return q2*q2*hsqrt(barrier4f(z0)/barrier4f(z));
}
// exp(-i a) via HW v_sin/v_cos (input in revolutions; |a|<=pi -> in range)
__device__ __forceinline__ cf epha(float a){
  const float r = a * 0.15915494309189535f;
  float c = __builtin_amdgcn_cosf(r);
  float s = __builtin_amdgcn_sinf(r);
  return mkcf(c, -s);
}

struct Ptrs { const float* p[28]; };

#define SCHED_WALL() __builtin_amdgcn_sched_barrier(0)

// ---------------- macro machinery (all indices literal -> pure SSA) ----------------
#define EF_LIST(X) X(0,0) X(0,1) X(0,2) X(1,0) X(1,1) X(1,2) X(2,0) X(2,1) X(2,2)

// e^{-i m phi} by index M = m+1
#define PH_0(E) cconj(E)
#define PH_1(E) mkcf(1.f,0.f)
#define PH_2(E) (E)
#define PH_(M,E) PH_##M(E)
#define PH(M,E)  PH_(M,E)

// d^1 entries by literal [R][C]
#define D1_00(P) (P##A2)
#define D1_01(P) (P##AB)
#define D1_02(P) (P##B2)
#define D1_10(P) (-(P##AB))
#define D1_11(P) (P##CC)
#define D1_12(P) (P##AB)
#define D1_20(P) (P##B2)
#define D1_21(P) (-(P##AB))
#define D1_22(P) (P##A2)
#define D1E_(R,C,P) D1_##R##C(P)
#define D1E(R,C,P)  D1E_(R,C,P)

#define MK_D1S(P, CB) \
  float P##A2 = 0.5f*(1.f+(CB)); \
  float P##B2 = 0.5f*(1.f-(CB)); \
  float P##AB = 1.4142135623730951f*hsqrt(fmaxf(0.f, P##A2*P##B2)); \
  float P##CC = P##A2 - P##B2;

// d^2 entries by literal [R][C] (cols 1..3 only)
#define D2_0_1 (w_a3)
#define D2_0_2 (w_u6)
#define D2_0_3 (w_b3)
#define D2_1_1 (w_c1)
#define D2_1_2 (w_t6)
#define D2_1_3 (w_c2)
#define D2_2_1 (-w_t6)
#define D2_2_2 (w_c0)
#define D2_2_3 (w_t6)
#define D2_3_1 (w_c2)
#define D2_3_2 (-w_t6)
#define D2_3_3 (w_c1)
#define D2_4_1 (-w_b3)
#define D2_4_2 (w_u6)
#define D2_4_3 (-w_a3)
#define D2E_(R,C) D2_##R##_##C
#define D2E(R,C)  D2E_(R,C)

// chain-local amplitude accumulators: A{a}_{e}{f}
#define DECL_A(E,F) cf A0_##E##F = mkcf(0.f,0.f); cf A1_##E##F = mkcf(0.f,0.f);
// LDS merge macros (per-thread private slots -> no syncs)
#define STORE1(E,F) accL[(E)*3+(F)][tid] = A0_##E##F; accL[18+(E)*3+(F)][tid] = A1_##E##F;
#define MERGE2(E,F) accL[(E)*3+(F)][tid] = cadd(accL[(E)*3+(F)][tid], A0_##E##F); \
                    accL[18+(E)*3+(F)][tid] = cadd(accL[18+(E)*3+(F)][tid], A1_##E##F);
#define FIN3(E,F) { cf s0 = cadd(accL[(E)*3+(F)][tid], A0_##E##F); psum += s0.x*s0.x + s0.y*s0.y; \
                    cf s1 = cadd(accL[18+(E)*3+(F)][tid], A1_##E##F); psum += s1.x*s1.x + s1.y*s1.y; }

// ---- Zc chain macros (restructured: inner contraction S shared across a=+-1) ----
#define MK_DD(W,F) cf DD_##W##F = cmulr(cmul(PH(W,eDa), PH(F,eDg)), D1E(W,F,v));
#define MK_DB(P,E) cf DB_##P##E = cmulr(cmul(PH(P,eBa), PH(E,eBg)), D1E(P,E,b));
#define MK_F2(P,W) cf F2_##P##W = cadd(cmulr(g2, ZT.F2[P][W][0]), \
                      cadd(cmulr(g3r, ZT.F2[P][W][1]), cmulr(g4r, ZT.F2[P][W][2])));

#define DECL_S(E,F) cf S_##E##F = mkcf(0.f,0.f);
#define ZC_SACC_E(P,E) \
  S_##E##0 = cadd(S_##E##0, cmul(DB_##P##E, G0)); \
  S_##E##1 = cadd(S_##E##1, cmul(DB_##P##E, G1)); \
  S_##E##2 = cadd(S_##E##2, cmul(DB_##P##E, G2));
#define ZC_SACC(P) ZC_SACC_E(P,0) ZC_SACC_E(P,1) ZC_SACC_E(P,2)

#define ZC_P0(R) { \
  cf t0 = cmulr(F2_00, D1E(R,1,r)); \
  cf t1 = cmulr(F2_01, D1E(R,0,r)); \
  cf G0 = cadd(cmul(t0, DD_00), cmul(t1, DD_10)); \
  cf G1 = cadd(cmul(t0, DD_01), cmul(t1, DD_11)); \
  cf G2 = cadd(cmul(t0, DD_02), cmul(t1, DD_12)); \
  ZC_SACC(0) }
#define ZC_P1(R) { \
  cf t0 = cmulr(F2_10, D1E(R,2,r)); \
  cf t1 = cmulr(F2_11, D1E(R,1,r)); \
  cf t2 = cmulr(F2_12, D1E(R,0,r)); \
  cf G0 = cadd(cadd(cmul(t0, DD_00), cmul(t1, DD_10)), cmul(t2, DD_20)); \
  cf G1 = cadd(cadd(cmul(t0, DD_01), cmul(t1, DD_11)), cmul(t2, DD_21)); \
  cf G2 = cadd(cadd(cmul(t0, DD_02), cmul(t1, DD_12)), cmul(t2, DD_22)); \
  ZC_SACC(1) }
#define ZC_P2(R) { \
  cf t1 = cmulr(F2_21, D1E(R,2,r)); \
  cf t2 = cmulr(F2_22, D1E(R,1,r)); \
  cf G0 = cadd(cmul(t1, DD_10), cmul(t2, DD_20)); \
  cf G1 = cadd(cmul(t1, DD_11), cmul(t2, DD_21)); \
  cf G2 = cadd(cmul(t1, DD_12), cmul(t2, DD_22)); \
  ZC_SACC(2) }

#define ZC_APPLY(E,F) \
  A0_##E##F = cadd(A0_##E##F, cmul(za0, S_##E##F)); \
  A1_##E##F = cadd(A1_##E##F, cmul(za1, S_##E##F));

#define ZC_R(R) { \
  cf F1c = cadd(cmulr(g0, ZT.F1[R][0]), cmulr(g1r, ZT.F1[R][1])); \
  cf Zr  = cmul(F1c, PH(R,eR)); \
  cf za0 = cmulr(cmul(Zr, Ua0), D1E(0,R,a)); \
  cf za1 = cmulr(cmul(Zr, Ua1), D1E(2,R,a)); \
  EF_LIST(DECL_S) \
  ZC_P0(R) ZC_P1(R) ZC_P2(R) \
  EF_LIST(ZC_APPLY) }

// ---- D2 chain macros ----
#define MK_DBG(P,E) cf dBg_##P##E = cmulr(PH(E,eBg), D1E(P,E,b));
#define D2_W(R) \
  cf t0 = cmulr(F2p_0, D2E(R,1)); \
  cf t1 = cmulr(F2p_1, D2E(R,2)); \
  cf t2 = cmulr(F2p_2, D2E(R,3)); \
  cf W0 = cadd(cadd(cmul(t0,dBg_00), cmul(t1,dBg_10)), cmul(t2,dBg_20)); \
  cf W1 = cadd(cadd(cmul(t0,dBg_01), cmul(t1,dBg_11)), cmul(t2,dBg_21)); \
  cf W2 = cadd(cadd(cmul(t0,dBg_02), cmul(t1,dBg_12)), cmul(t2,dBg_22));
#define D2F(R,F,K1) { \
  cf zf = cmulr(g5, D2T.F1[R][F][0]); \
  zf = cadd(zf, cmulr(g6r, D2T.F1[R][F][1])); \
  zf = cadd(zf, cmulr(g7r, D2T.F1[R][F][2])); \
  zf = cadd(zf, cmulr(g8r, D2T.F1[R][F][3])); \
  zf = cadd(zf, cmulr(g9r, D2T.F1[R][F][4])); \
  cf z0 = cmulr(cmul(zf, Zb0), D1E(0,K1,a)); \
  cf z1 = cmulr(cmul(zf, Zb1), D1E(2,K1,a)); \
  A0_0##F = cadd(A0_0##F, cmul(z0, W0)); A1_0##F = cadd(A1_0##F, cmul(z1, W0)); \
  A0_1##F = cadd(A0_1##F, cmul(z0, W1)); A1_1##F = cadd(A1_1##F, cmul(z1, W1)); \
  A0_2##F = cadd(A0_2##F, cmul(z0, W2)); A1_2##F = cadd(A1_2##F, cmul(z1, W2)); }

// ---- D1 chain macros ----
#define MK_DDG(W,F) cf dDg_##W##F = cmulr(PH(F,eDg), D1E(W,F,v));
#define D1_G(R) \
  cf t0 = cmulr(F2p_0, D1E(R,0,r)); \
  cf t1 = cmulr(F2p_1, D1E(R,1,r)); \
  cf t2 = cmulr(F2p_2, D1E(R,2,r)); \
  cf G0 = cadd(cadd(cmul(t0,dDg_00), cmul(t1,dDg_10)), cmul(t2,dDg_20)); \
  cf G1 = cadd(cadd(cmul(t0,dDg_01), cmul(t1,dDg_11)), cmul(t2,dDg_21)); \
  cf G2 = cadd(cadd(cmul(t0,dDg_02), cmul(t1,dDg_12)), cmul(t2,dDg_22));
#define D1F(R,E,K1) { \
  cf ze = cmulr(g11, D1T.F1[R][E][0]); \
  ze = cadd(ze, cmulr(g12r, D1T.F1[R][E][1])); \
  ze = cadd(ze, cmulr(g13r, D1T.F1[R][E][2])); \
  cf z0 = cmulr(cmul(ze, Zb0), D1E(0,K1,a)); \
  cf z1 = cmulr(cmul(ze, Zb1), D1E(2,K1,a)); \
  A0_##E##0 = cadd(A0_##E##0, cmul(z0, G0)); A1_##E##0 = cadd(A1_##E##0, cmul(z1, G0)); \
  A0_##E##1 = cadd(A0_##E##1, cmul(z0, G1)); A1_##E##1 = cadd(A1_##E##1, cmul(z1, G1)); \
  A0_##E##2 = cadd(A0_##E##2, cmul(z0, G2)); A1_##E##2 = cadd(A1_##E##2, cmul(z1, G2)); }

// ---------------- kernel ----------------
__global__ __launch_bounds__(128, 2) void amp_kernel(Ptrs P, float* __restrict__ out, int N){
  const int tid = threadIdx.x;
  const int gid = blockIdx.x * blockDim.x + tid;
  __shared__ cf accL[36][128];   // per-thread private cross-chain accumulator (36.9 KB)
  float psum = 0.f;
  if (gid < N) {
    const int n = gid;
    const float* __restrict__ gls = P.p[27];

    //=========== Zc_4025 (BD chain, Jr=1) ===========
    {
      EF_LIST(DECL_A)
      const float m    = P.p[8][n];
      const float phiA = P.p[9][n];
      const float cosA = P.p[10][n];
      const float phiR = P.p[11][n];
      const float cosR = P.p[12][n];
      const float aBv  = P.p[13][n];
      const float cbB  = P.p[14][n];
      const float gBv  = P.p[15][n];
      const float aDv  = P.p[16][n];
      const float cbD  = P.p[17][n];
      const float gDv  = P.p[18][n];

      cf g0=mkcf(gls[0],gls[1]), g1=mkcf(gls[2],gls[3]), g2=mkcf(gls[4],gls[5]),
         g3=mkcf(gls[6],gls[7]), g4=mkcf(gls[8],gls[9]);

      float q_rt = getqf(ECOMf, M0Cf, m);
      float q_nd = getqf(m, M0Bf, M0Df);
      float r2rt = rad2f(q_rt, ZC_Q0RT);
      float r2nd = rad2f(q_nd, ZC_Q0ND);

      float width = 0.025f * (q_nd * (1.f/ZC_Q0BW)) * (4.026f / m);
      float dre = m*m - 4.026f*4.026f, dim_ = 4.026f*width;
      float inv = 1.f/(dre*dre + dim_*dim_);
      cf bw = mkcf(dre*inv, -dim_*inv);

      cf eA = epha(phiA); cf eAc = cconj(eA);
      cf eR = epha(phiR), eBa = epha(aBv), eBg = epha(gBv), eDa = epha(aDv), eDg = epha(gDv);
      cf Ua0 = cmul(bw, eAc);
      cf Ua1 = cmul(bw, eA);

      MK_D1S(a, cosA)
      MK_D1S(r, cosR)
      MK_D1S(b, cbB)
      MK_D1S(v, cbD)

      cf g1r = cmulr(g1, r2rt);
      cf g3r = cmulr(g3, r2nd);
      cf g4r = cmulr(g4, r2nd);

      EF_LIST(MK_DD)
      EF_LIST(MK_DB)
      EF_LIST(MK_F2)
      ZC_R(0) ZC_R(1) ZC_R(2)

      EF_LIST(STORE1)
    }

    SCHED_WALL();

    //=========== D2_2460 (BC chain, Jr=2) ===========
    {
      EF_LIST(DECL_A)
      const float m    = P.p[0][n];
      const float phiA = P.p[1][n];
      const float cosA = P.p[2][n];
      const float phiR = P.p[3][n];
      const float cosR = P.p[4][n];
      const float aBv  = P.p[5][n];
      const float cbB  = P.p[6][n];
      const float gBv  = P.p[7][n];

      cf g5=mkcf(gls[10],gls[11]), g6=mkcf(gls[12],gls[13]), g7=mkcf(gls[14],gls[15]),
         g8=mkcf(gls[16],gls[17]), g9=mkcf(gls[18],gls[19]), g10=mkcf(gls[20],gls[21]);

      float q_rt = getqf(ECOMf, M0Df, m);
      float q_nd = getqf(m, M0Bf, M0Cf);
      float r2rt = rad2f(q_rt, D2_Q0RT);
      float r4rt = rad4f(q_rt, D2_Q0RT);
      float r2nd = rad2f(q_nd, D2_Q0ND);

      float z = 9.f*q_nd*q_nd;
      float bpr2 = barrier2f(9.f*D2_Q0ND*D2_Q0ND)/barrier2f(z);
      float qr = q_nd*(1.f/D2_Q0ND);
      float width = 0.0475f * qr*qr*qr*qr*qr * (2.4607f/m) * bpr2;
      float dre = m*m - 2.4607f*2.4607f, dim_ = 2.4607f*width;
      float inv = 1.f/(dre*dre + dim_*dim_);
      cf bw = mkcf(dre*inv, -dim_*inv);

      cf eA = epha(phiA); cf eAc = cconj(eA);
      cf eR = epha(phiR), eBa = epha(aBv), eBg = epha(gBv);
      cf eR2 = cmul(eR, eR);

      MK_D1S(a, cosA)
      MK_D1S(b, cbB)

      float w_A2 = 0.5f*(1.f+cosR);
      float w_B2 = 0.5f*(1.f-cosR);
      float w_u  = w_A2*w_B2;
      float w_AB = hsqrt(fmaxf(0.f, w_u));
      const float R6 = 2.449489742783178f;
      float w_a3 = 2.f*w_A2*w_AB, w_b3 = 2.f*w_B2*w_AB;
      float w_t6 = R6*w_AB*(w_A2-w_B2), w_u6 = R6*w_u;
      float w_c1 = w_A2*w_A2 - 3.f*w_u;
      float w_c2 = 3.f*w_u - w_B2*w_B2;
      float w_c0 = w_A2*w_A2 - 4.f*w_u + w_B2*w_B2;

      cf g6r = cmulr(g6, r2rt), g7r = cmulr(g7, r2rt), g8r = cmulr(g8, r2rt);
      cf g9r = cmulr(g9, r4rt);
      cf g10r = cmulr(g10, r2nd);

      cf F2p_0 = cmul(cmulr(g10r, D2T.F2[0]), PH(0,eBa));
      cf F2p_1 = cmul(cmulr(g10r, D2T.F2[1]), PH(1,eBa));
      cf F2p_2 = cmul(cmulr(g10r, D2T.F2[2]), PH(2,eBa));

      EF_LIST(MK_DBG)

      { cf zb = cmul(bw, cconj(eR2)); cf Zb0 = cmul(zb, eAc), Zb1 = cmul(zb, eA);
        D2_W(0) D2F(0,0,0) }
      { cf zb = cmul(bw, cconj(eR));  cf Zb0 = cmul(zb, eAc), Zb1 = cmul(zb, eA);
        D2_W(1) D2F(1,0,1) D2F(1,1,0) }
      { cf zb = bw;                   cf Zb0 = cmul(zb, eAc), Zb1 = cmul(zb, eA);
        D2_W(2) D2F(2,0,2) D2F(2,1,1) D2F(2,2,0) }
      { cf zb = cmul(bw, eR);         cf Zb0 = cmul(zb, eAc), Zb1 = cmul(zb, eA);
        D2_W(3) D2F(3,1,2) D2F(3,2,1) }
      { cf zb = cmul(bw, eR2);        cf Zb0 = cmul(zb, eAc), Zb1 = cmul(zb, eA);
        D2_W(4) D2F(4,2,2) }

      EF_LIST(MERGE2)
    }

    SCHED_WALL();

    //=========== D1_2430 (CD chain, Jr=1) ===========
    {
      EF_LIST(DECL_A)
      const float m    = P.p[19][n];
      const float phiA = P.p[20][n];
      const float cosA = P.p[21][n];
      const float phiR = P.p[22][n];
      const float cosR = P.p[23][n];
      const float aDv  = P.p[24][n];
      const float cbD  = P.p[25][n];
      const float gDv  = P.p[26][n];

      cf g11=mkcf(gls[22],gls[23]), g12=mkcf(gls[24],gls[25]), g13=mkcf(gls[26],gls[27]),
         g14=mkcf(gls[28],gls[29]), g15=mkcf(gls[30],gls[31]);

      float q_rt = getqf(ECOMf, M0Bf, m);
      float q_nd = getqf(m, M0Cf, M0Df);
      float r2rt = rad2f(q_rt, D1_Q0RT);
      float r2nd = rad2f(q_nd, D1_Q0ND);

      float width = 0.384f * (q_nd*(1.f/D1_Q0ND)) * (2.427f/m);
      float dre = m*m - 2.427f*2.427f, dim_ = 2.427f*width;
      float inv = 1.f/(dre*dre + dim_*dim_);
      cf bw = mkcf(dre*inv, -dim_*inv);

      cf eA = epha(phiA); cf eAc = cconj(eA);
      cf eR = epha(phiR), eDa = epha(aDv), eDg = epha(gDv);

      MK_D1S(a, cosA)
      MK_D1S(r, cosR)
      MK_D1S(v, cbD)

      cf g12r = cmulr(g12, r2rt), g13r = cmulr(g13, r2rt);
      cf g15r = cmulr(g15, r2nd);

      cf F2p_0 = cmul(cadd(cmulr(g14, D1T.F2[0][0]), cmulr(g15r, D1T.F2[0][1])), PH(0,eDa));
      cf F2p_1 = cmul(cadd(cmulr(g14, D1T.F2[1][0]), cmulr(g15r, D1T.F2[1][1])), PH(1,eDa));
      cf F2p_2 = cmul(cadd(cmulr(g14, D1T.F2[2][0]), cmulr(g15r, D1T.F2[2][1])), PH(2,eDa));

      EF_LIST(MK_DDG)

      { cf zb = cmul(bw, cconj(eR)); cf Zb0 = cmul(zb, eAc), Zb1 = cmul(zb, eA);
        D1_G(0) D1F(0,0,1) D1F(0,1,0) }
      { cf zb = bw;                  cf Zb0 = cmul(zb, eAc), Zb1 = cmul(zb, eA);
        D1_G(1) D1F(1,0,2) D1F(1,1,1) D1F(1,2,0) }
      { cf zb = cmul(bw, eR);        cf Zb0 = cmul(zb, eAc), Zb1 = cmul(zb, eA);
        D1_G(2) D1F(2,1,2) D1F(2,2,1) }

      EF_LIST(FIN3)
    }
  }

  // wave + block reduction, one atomic per block (128 threads = 2 waves)
  #pragma unroll
  for (int off=32; off>0; off>>=1) psum += __shfl_down(psum, off, 64);
  __shared__ float red[2];
  int lane = threadIdx.x & 63, wid = threadIdx.x >> 6;
  if (lane == 0) red[wid] = psum;
  __syncthreads();
  if (threadIdx.x == 0) atomicAdd(out, red[0]+red[1]);
}

// ---------------- launch ----------------
extern "C" void kernel_launch(void* const* d_in, const int* in_sizes, int n_in,
                              void* d_out, int out_size, void* d_ws, size_t ws_size,
                              hipStream_t stream){
  (void)n_in; (void)d_ws; (void)ws_size;
  Ptrs P;
  for (int i=0; i<28; ++i) P.p[i] = (const float*)d_in[i];
  int N = in_sizes[0];
  hipMemsetAsync(d_out, 0, (size_t)out_size * sizeof(float), stream);
  int grid = (N + 127) / 128;
  amp_kernel<<<grid, 128, 0, stream>>>(P, (float*)d_out, N);
}

// Round 9
// 71.654 us; speedup vs baseline: 1.0889x; 1.0071x over previous
//
#include <hip/hip_runtime.h>
#include <math.h>

#if defined(__clang__)
#pragma float_control(precise, off)
#endif

// ---------------- compile-time coefficient generation ----------------
constexpr double cfact(int n){ double r=1.0; for (int i=2;i<=n;++i) r*=(double)i; return r; }
constexpr double csq(double x){
  if (x<=0.0) return 0.0;
  double g = x<1.0 ? 1.0 : x;
  for (int i=0;i<64;++i) g = 0.5*(g + x/g);
  return g;
}
constexpr double ccg(int j1,int j2,int m1,int m2,int j,int m){
  if (m1+m2 != m) return 0.0;
  int lo = j1-j2; if (lo<0) lo = -lo;
  if (j < lo || j > j1+j2) return 0.0;
  int am1 = m1<0?-m1:m1, am2 = m2<0?-m2:m2, am = m<0?-m:m;
  if (am1>j1 || am2>j2 || am>j) return 0.0;
  double pref = csq((2.0*j+1.0)*cfact(j+j1-j2)*cfact(j-j1+j2)*cfact(j1+j2-j)/cfact(j1+j2+j+1));
  pref = pref * csq(cfact(j+m)*cfact(j-m)*cfact(j1-m1)*cfact(j1+m1)*cfact(j2-m2)*cfact(j2+m2));
  double tot = 0.0;
  for (int k=0; k<=j1+j2-j; ++k){
    int d0=k, d1=j1+j2-j-k, d2=j1-m1-k, d3=j2+m2-k, d4=j-j2+m1+k, d5=j-j1-m2+k;
    if (d0<0||d1<0||d2<0||d3<0||d4<0||d5<0) continue;
    double p = cfact(d0)*cfact(d1)*cfact(d2)*cfact(d3)*cfact(d4)*cfact(d5);
    tot += ((k&1)? -1.0 : 1.0)/p;
  }
  return pref*tot;
}
constexpr double cq(double m, double m1, double m2){
  double ms=m1+m2, md=m1-m2;
  return csq((m+ms)*(m-ms)*(m+md)*(m-md))/(2.0*m);
}

struct ZcTab { float F1[3][2]; float F2[3][3][3]; };
constexpr ZcTab mkZcT(){
  ZcTab t{};
  const int l0l[2]={0,2}; const int l0s[2]={1,1};
  for (int ir=0; ir<3; ++ir){
    int r = ir-1;
    for (int i=0;i<2;++i){
      int l=l0l[i], s=l0s[i];
      t.F1[ir][i] = (float)( csq((2.0*l+1.0)/3.0)*ccg(1,0,r,0,s,r)*ccg(l,s,0,r,1,r) );
    }
  }
  const int l1l[3]={0,2,2}; const int l1s[3]={1,1,2};
  for (int ip=0; ip<3; ++ip) for (int iw=0; iw<3; ++iw){
    int p=ip-1, w=iw-1;
    for (int i=0;i<3;++i){
      int l=l1l[i], s=l1s[i];
      t.F2[ip][iw][i] = (float)( csq((2.0*l+1.0)/3.0)*ccg(1,1,p,-w,s,p-w)*ccg(l,s,0,p-w,1,p-w) );
    }
  }
  return t;
}
struct D2Tab { float F1[5][3][5]; float F2[3]; };
constexpr D2Tab mkD2T(){
  D2Tab t{};
  const int l0l[5]={0,2,2,2,4}; const int l0s[5]={1,1,2,3,3};
  for (int ir=0;ir<5;++ir) for (int jf=0;jf<3;++jf){
    int r=ir-2, f=jf-1;
    for (int i=0;i<5;++i){
      int l=l0l[i], s=l0s[i];
      t.F1[ir][jf][i] = (float)( csq((2.0*l+1.0)/3.0)*ccg(2,1,r,-f,s,r-f)*ccg(l,s,0,r-f,1,r-f) );
    }
  }
  for (int ip=0;ip<3;++ip){
    int p=ip-1;
    t.F2[ip] = (float)( ccg(1,0,p,0,1,p)*ccg(2,1,0,p,2,p) );
  }
  return t;
}
struct D1Tab { float F1[3][3][3]; float F2[3][2]; };
constexpr D1Tab mkD1T(){
  D1Tab t{};
  const int l0l[3]={0,2,2}; const int l0s[3]={1,1,2};
  for (int ir=0;ir<3;++ir) for (int ie=0;ie<3;++ie){
    int r=ir-1, e=ie-1;
    for (int i=0;i<3;++i){
      int l=l0l[i], s=l0s[i];
      t.F1[ir][ie][i] = (float)( csq((2.0*l+1.0)/3.0)*ccg(1,1,r,-e,s,r-e)*ccg(l,s,0,r-e,1,r-e) );
    }
  }
  const int l1l[2]={0,2}; const int l1s[2]={1,1};
  for (int iw=0;iw<3;++iw){
    int w=iw-1;
    for (int i=0;i<2;++i){
      int l=l1l[i], s=l1s[i];
      t.F2[iw][i] = (float)( csq((2.0*l+1.0)/3.0)*ccg(0,1,w,0,s,w)*ccg(l,s,0,w,1,w) );
    }
  }
  return t;
}
constexpr ZcTab ZT  = mkZcT();
constexpr D2Tab D2T = mkD2T();
constexpr D1Tab D1T = mkD1T();

constexpr double ECd=4.59925, MBd=2.01026, MCd=0.13957061, MDd=2.00685;
constexpr float ZC_Q0RT = (float)cq(ECd, MCd, 4.026);
constexpr float ZC_Q0ND = (float)cq(4.026, MBd, MCd);
constexpr float ZC_Q0BW = (float)cq(4.026, MBd, MDd);
constexpr float D2_Q0RT = (float)cq(ECd, MDd, 2.4607);
constexpr float D2_Q0ND = (float)cq(2.4607, MBd, MCd);
constexpr float D1_Q0RT = (float)cq(ECd, MBd, 2.427);
constexpr float D1_Q0ND = (float)cq(2.427, MCd, MDd);

#define ECOMf 4.59925f
#define M0Bf  2.01026f
#define M0Cf  0.13957061f
#define M0Df  2.00685f

// ---------------- complex as packed float2 (targets v_pk_*_f32 VOP3P) ----------------
typedef float cf __attribute__((ext_vector_type(2)));
__device__ __forceinline__ cf mkcf(float x, float y){ cf r; r.x = x; r.y = y; return r; }
__device__ __forceinline__ cf cadd(cf a, cf b){ return a + b; }
__device__ __forceinline__ cf cmulr(cf a, float s){ return a * s; }
__device__ __forceinline__ cf cconj(cf a){ return mkcf(a.x, -a.y); }
// (ax*bx - ay*by, ax*by + ay*bx) = a.xx*b + a.yy*(-b.y, b.x)  -> 2x v_pk_fma_f32
__device__ __forceinline__ cf cmul(cf a, cf b){
  return a.xx * b + a.yy * mkcf(-b.y, b.x);
}

__device__ __forceinline__ float hsqrt(float x){ return __builtin_amdgcn_sqrtf(x); }

__device__ __forceinline__ float getqf(float m, float m1, float m2){
  float ms = m1+m2, md = m1-m2;
  return hsqrt((m+ms)*(m-ms)*(m+md)*(m-md))/(2.f*m);
}
__device__ __forceinline__ float barrier2f(float z){ return 9.f + (3.f+z)*z; }
__device__ __forceinline__ float barrier4f(float z){ return z*(z*(z*(z+10.f)+135.f)+1575.f)+11025.f; }
__device__ __forceinline__ float rad2f(float q, float q0){
  float z = 9.f*q*q, z0 = 9.f*q0*q0;
  return q*q*hsqrt(barrier2f(z0)/barrier2f(z));
}
__device__ __forceinline__ float rad4f(float q, float q0){
  float z = 9.f*q*q, z0 = 9.f*q0*q0;
  float q2 = q*q;
  return q2*q2*hsqrt(barrier4f(z0)/barrier4f(z));
}
// exp(-i a) via HW v_sin/v_cos (input in revolutions; |a|<=pi -> in range)
__device__ __forceinline__ cf epha(float a){
  const float r = a * 0.15915494309189535f;
  float c = __builtin_amdgcn_cosf(r);
  float s = __builtin_amdgcn_sinf(r);
  return mkcf(c, -s);
}

struct Ptrs { const float* p[28]; };

// VALU pinned; SALU + all VMEM may cross (lets loads prefetch across chains)
#define SCHED_WALL() __builtin_amdgcn_sched_barrier(0x74)

// ---------------- macro machinery (all indices literal -> pure SSA) ----------------
#define EF_LIST(X) X(0,0) X(0,1) X(0,2) X(1,0) X(1,1) X(1,2) X(2,0) X(2,1) X(2,2)

// e^{-i m phi} by index M = m+1
#define PH_0(E) cconj(E)
#define PH_1(E) mkcf(1.f,0.f)
#define PH_2(E) (E)
#define PH_(M,E) PH_##M(E)
#define PH(M,E)  PH_(M,E)

// d^1 entries by literal [R][C]
#define D1_00(P) (P##A2)
#define D1_01(P) (P##AB)
#define D1_02(P) (P##B2)
#define D1_10(P) (-(P##AB))
#define D1_11(P) (P##CC)
#define D1_12(P) (P##AB)
#define D1_20(P) (P##B2)
#define D1_21(P) (-(P##AB))
#define D1_22(P) (P##A2)
#define D1E_(R,C,P) D1_##R##C(P)
#define D1E(R,C,P)  D1E_(R,C,P)

#define MK_D1S(P, CB) \
  float P##A2 = 0.5f*(1.f+(CB)); \
  float P##B2 = 0.5f*(1.f-(CB)); \
  float P##AB = 1.4142135623730951f*hsqrt(fmaxf(0.f, P##A2*P##B2)); \
  float P##CC = P##A2 - P##B2;

// d^2 entries by literal [R][C] (cols 1..3 only)
#define D2_0_1 (w_a3)
#define D2_0_2 (w_u6)
#define D2_0_3 (w_b3)
#define D2_1_1 (w_c1)
#define D2_1_2 (w_t6)
#define D2_1_3 (w_c2)
#define D2_2_1 (-w_t6)
#define D2_2_2 (w_c0)
#define D2_2_3 (w_t6)
#define D2_3_1 (w_c2)
#define D2_3_2 (-w_t6)
#define D2_3_3 (w_c1)
#define D2_4_1 (-w_b3)
#define D2_4_2 (w_u6)
#define D2_4_3 (-w_a3)
#define D2E_(R,C) D2_##R##_##C
#define D2E(R,C)  D2E_(R,C)

// global amplitude accumulators (live across all three chains, in registers)
#define DECL_A(E,F) cf A0_##E##F = mkcf(0.f,0.f); cf A1_##E##F = mkcf(0.f,0.f);
#define SUMSQ(E,F) psum += A0_##E##F.x*A0_##E##F.x + A0_##E##F.y*A0_##E##F.y \
                        + A1_##E##F.x*A1_##E##F.x + A1_##E##F.y*A1_##E##F.y;

// ---- Zc chain macros (inner contraction S shared across a=+-1) ----
#define MK_DD(W,F) cf DD_##W##F = cmulr(cmul(PH(W,eDa), PH(F,eDg)), D1E(W,F,v));
#define MK_DB(P,E) cf DB_##P##E = cmulr(cmul(PH(P,eBa), PH(E,eBg)), D1E(P,E,b));
#define MK_F2(P,W) cf F2_##P##W = cadd(cmulr(g2, ZT.F2[P][W][0]), \
                      cadd(cmulr(g3r, ZT.F2[P][W][1]), cmulr(g4r, ZT.F2[P][W][2])));

#define DECL_S(E,F) cf S_##E##F = mkcf(0.f,0.f);
#define ZC_SACC_E(P,E) \
  S_##E##0 = cadd(S_##E##0, cmul(DB_##P##E, G0)); \
  S_##E##1 = cadd(S_##E##1, cmul(DB_##P##E, G1)); \
  S_##E##2 = cadd(S_##E##2, cmul(DB_##P##E, G2));
#define ZC_SACC(P) ZC_SACC_E(P,0) ZC_SACC_E(P,1) ZC_SACC_E(P,2)

#define ZC_P0(R) { \
  cf t0 = cmulr(F2_00, D1E(R,1,r)); \
  cf t1 = cmulr(F2_01, D1E(R,0,r)); \
  cf G0 = cadd(cmul(t0, DD_00), cmul(t1, DD_10)); \
  cf G1 = cadd(cmul(t0, DD_01), cmul(t1, DD_11)); \
  cf G2 = cadd(cmul(t0, DD_02), cmul(t1, DD_12)); \
  ZC_SACC(0) }
#define ZC_P1(R) { \
  cf t0 = cmulr(F2_10, D1E(R,2,r)); \
  cf t1 = cmulr(F2_11, D1E(R,1,r)); \
  cf t2 = cmulr(F2_12, D1E(R,0,r)); \
  cf G0 = cadd(cadd(cmul(t0, DD_00), cmul(t1, DD_10)), cmul(t2, DD_20)); \
  cf G1 = cadd(cadd(cmul(t0, DD_01), cmul(t1, DD_11)), cmul(t2, DD_21)); \
  cf G2 = cadd(cadd(cmul(t0, DD_02), cmul(t1, DD_12)), cmul(t2, DD_22)); \
  ZC_SACC(1) }
#define ZC_P2(R) { \
  cf t1 = cmulr(F2_21, D1E(R,2,r)); \
  cf t2 = cmulr(F2_22, D1E(R,1,r)); \
  cf G0 = cadd(cmul(t1, DD_10), cmul(t2, DD_20)); \
  cf G1 = cadd(cmul(t1, DD_11), cmul(t2, DD_21)); \
  cf G2 = cadd(cmul(t1, DD_12), cmul(t2, DD_22)); \
  ZC_SACC(2) }

#define ZC_APPLY(E,F) \
  A0_##E##F = cadd(A0_##E##F, cmul(za0, S_##E##F)); \
  A1_##E##F = cadd(A1_##E##F, cmul(za1, S_##E##F));

#define ZC_R(R) { \
  cf F1c = cadd(cmulr(g0, ZT.F1[R][0]), cmulr(g1r, ZT.F1[R][1])); \
  cf Zr  = cmul(F1c, PH(R,eR)); \
  cf za0 = cmulr(cmul(Zr, Ua0), D1E(0,R,a)); \
  cf za1 = cmulr(cmul(Zr, Ua1), D1E(2,R,a)); \
  EF_LIST(DECL_S) \
  ZC_P0(R) ZC_P1(R) ZC_P2(R) \
  EF_LIST(ZC_APPLY) }

// ---- D2 chain macros ----
#define MK_DBG(P,E) cf dBg_##P##E = cmulr(PH(E,eBg), D1E(P,E,b));
#define D2_W(R) \
  cf t0 = cmulr(F2p_0, D2E(R,1)); \
  cf t1 = cmulr(F2p_1, D2E(R,2)); \
  cf t2 = cmulr(F2p_2, D2E(R,3)); \
  cf W0 = cadd(cadd(cmul(t0,dBg_00), cmul(t1,dBg_10)), cmul(t2,dBg_20)); \
  cf W1 = cadd(cadd(cmul(t0,dBg_01), cmul(t1,dBg_11)), cmul(t2,dBg_21)); \
  cf W2 = cadd(cadd(cmul(t0,dBg_02), cmul(t1,dBg_12)), cmul(t2,dBg_22));
#define D2F(R,F,K1) { \
  cf zf = cmulr(g5, D2T.F1[R][F][0]); \
  zf = cadd(zf, cmulr(g6r, D2T.F1[R][F][1])); \
  zf = cadd(zf, cmulr(g7r, D2T.F1[R][F][2])); \
  zf = cadd(zf, cmulr(g8r, D2T.F1[R][F][3])); \
  zf = cadd(zf, cmulr(g9r, D2T.F1[R][F][4])); \
  cf z0 = cmulr(cmul(zf, Zb0), D1E(0,K1,a)); \
  cf z1 = cmulr(cmul(zf, Zb1), D1E(2,K1,a)); \
  A0_0##F = cadd(A0_0##F, cmul(z0, W0)); A1_0##F = cadd(A1_0##F, cmul(z1, W0)); \
  A0_1##F = cadd(A0_1##F, cmul(z0, W1)); A1_1##F = cadd(A1_1##F, cmul(z1, W1)); \
  A0_2##F = cadd(A0_2##F, cmul(z0, W2)); A1_2##F = cadd(A1_2##F, cmul(z1, W2)); }

// ---- D1 chain macros ----
#define MK_DDG(W,F) cf dDg_##W##F = cmulr(PH(F,eDg), D1E(W,F,v));
#define D1_G(R) \
  cf t0 = cmulr(F2p_0, D1E(R,0,r)); \
  cf t1 = cmulr(F2p_1, D1E(R,1,r)); \
  cf t2 = cmulr(F2p_2, D1E(R,2,r)); \
  cf G0 = cadd(cadd(cmul(t0,dDg_00), cmul(t1,dDg_10)), cmul(t2,dDg_20)); \
  cf G1 = cadd(cadd(cmul(t0,dDg_01), cmul(t1,dDg_11)), cmul(t2,dDg_21)); \
  cf G2 = cadd(cadd(cmul(t0,dDg_02), cmul(t1,dDg_12)), cmul(t2,dDg_22));
#define D1F(R,E,K1) { \
  cf ze = cmulr(g11, D1T.F1[R][E][0]); \
  ze = cadd(ze, cmulr(g12r, D1T.F1[R][E][1])); \
  ze = cadd(ze, cmulr(g13r, D1T.F1[R][E][2])); \
  cf z0 = cmulr(cmul(ze, Zb0), D1E(0,K1,a)); \
  cf z1 = cmulr(cmul(ze, Zb1), D1E(2,K1,a)); \
  A0_##E##0 = cadd(A0_##E##0, cmul(z0, G0)); A1_##E##0 = cadd(A1_##E##0, cmul(z1, G0)); \
  A0_##E##1 = cadd(A0_##E##1, cmul(z0, G1)); A1_##E##1 = cadd(A1_##E##1, cmul(z1, G1)); \
  A0_##E##2 = cadd(A0_##E##2, cmul(z0, G2)); A1_##E##2 = cadd(A1_##E##2, cmul(z1, G2)); }

// ---------------- kernel ----------------
__global__ __launch_bounds__(128, 3) void amp_kernel(Ptrs P, float* __restrict__ out, int N){
  const int tid = threadIdx.x;
  const int gid = blockIdx.x * blockDim.x + tid;
  float psum = 0.f;
  if (gid < N) {
    const int n = gid;
    const float* __restrict__ gls = P.p[27];

    EF_LIST(DECL_A)

    //=========== Zc_4025 (BD chain, Jr=1) ===========
    {
      const float m    = P.p[8][n];
      const float phiA = P.p[9][n];
      const float cosA = P.p[10][n];
      const float phiR = P.p[11][n];
      const float cosR = P.p[12][n];
      const float aBv  = P.p[13][n];
      const float cbB  = P.p[14][n];
      const float gBv  = P.p[15][n];
      const float aDv  = P.p[16][n];
      const float cbD  = P.p[17][n];
      const float gDv  = P.p[18][n];

      cf g0=mkcf(gls[0],gls[1]), g1=mkcf(gls[2],gls[3]), g2=mkcf(gls[4],gls[5]),
         g3=mkcf(gls[6],gls[7]), g4=mkcf(gls[8],gls[9]);

      float q_rt = getqf(ECOMf, M0Cf, m);
      float q_nd = getqf(m, M0Bf, M0Df);
      float r2rt = rad2f(q_rt, ZC_Q0RT);
      float r2nd = rad2f(q_nd, ZC_Q0ND);

      float width = 0.025f * (q_nd * (1.f/ZC_Q0BW)) * (4.026f / m);
      float dre = m*m - 4.026f*4.026f, dim_ = 4.026f*width;
      float inv = 1.f/(dre*dre + dim_*dim_);
      cf bw = mkcf(dre*inv, -dim_*inv);

      cf eA = epha(phiA); cf eAc = cconj(eA);
      cf eR = epha(phiR), eBa = epha(aBv), eBg = epha(gBv), eDa = epha(aDv), eDg = epha(gDv);
      cf Ua0 = cmul(bw, eAc);
      cf Ua1 = cmul(bw, eA);

      MK_D1S(a, cosA)
      MK_D1S(r, cosR)
      MK_D1S(b, cbB)
      MK_D1S(v, cbD)

      cf g1r = cmulr(g1, r2rt);
      cf g3r = cmulr(g3, r2nd);
      cf g4r = cmulr(g4, r2nd);

      EF_LIST(MK_DD)
      EF_LIST(MK_DB)
      EF_LIST(MK_F2)
      ZC_R(0) ZC_R(1) ZC_R(2)
    }

    SCHED_WALL();

    //=========== D2_2460 (BC chain, Jr=2) ===========
    {
      const float m    = P.p[0][n];
      const float phiA = P.p[1][n];
      const float cosA = P.p[2][n];
      const float phiR = P.p[3][n];
      const float cosR = P.p[4][n];
      const float aBv  = P.p[5][n];
      const float cbB  = P.p[6][n];
      const float gBv  = P.p[7][n];

      cf g5=mkcf(gls[10],gls[11]), g6=mkcf(gls[12],gls[13]), g7=mkcf(gls[14],gls[15]),
         g8=mkcf(gls[16],gls[17]), g9=mkcf(gls[18],gls[19]), g10=mkcf(gls[20],gls[21]);

      float q_rt = getqf(ECOMf, M0Df, m);
      float q_nd = getqf(m, M0Bf, M0Cf);
      float r2rt = rad2f(q_rt, D2_Q0RT);
      float r4rt = rad4f(q_rt, D2_Q0RT);
      float r2nd = rad2f(q_nd, D2_Q0ND);

      float z = 9.f*q_nd*q_nd;
      float bpr2 = barrier2f(9.f*D2_Q0ND*D2_Q0ND)/barrier2f(z);
      float qr = q_nd*(1.f/D2_Q0ND);
      float width = 0.0475f * qr*qr*qr*qr*qr * (2.4607f/m) * bpr2;
      float dre = m*m - 2.4607f*2.4607f, dim_ = 2.4607f*width;
      float inv = 1.f/(dre*dre + dim_*dim_);
      cf bw = mkcf(dre*inv, -dim_*inv);

      cf eA = epha(phiA); cf eAc = cconj(eA);
      cf eR = epha(phiR), eBa = epha(aBv), eBg = epha(gBv);
      cf eR2 = cmul(eR, eR);

      MK_D1S(a, cosA)
      MK_D1S(b, cbB)

      float w_A2 = 0.5f*(1.f+cosR);
      float w_B2 = 0.5f*(1.f-cosR);
      float w_u  = w_A2*w_B2;
      float w_AB = hsqrt(fmaxf(0.f, w_u));
      const float R6 = 2.449489742783178f;
      float w_a3 = 2.f*w_A2*w_AB, w_b3 = 2.f*w_B2*w_AB;
      float w_t6 = R6*w_AB*(w_A2-w_B2), w_u6 = R6*w_u;
      float w_c1 = w_A2*w_A2 - 3.f*w_u;
      float w_c2 = 3.f*w_u - w_B2*w_B2;
      float w_c0 = w_A2*w_A2 - 4.f*w_u + w_B2*w_B2;

      cf g6r = cmulr(g6, r2rt), g7r = cmulr(g7, r2rt), g8r = cmulr(g8, r2rt);
      cf g9r = cmulr(g9, r4rt);
      cf g10r = cmulr(g10, r2nd);

      cf F2p_0 = cmul(cmulr(g10r, D2T.F2[0]), PH(0,eBa));
      cf F2p_1 = cmul(cmulr(g10r, D2T.F2[1]), PH(1,eBa));
      cf F2p_2 = cmul(cmulr(g10r, D2T.F2[2]), PH(2,eBa));

      EF_LIST(MK_DBG)

      { cf zb = cmul(bw, cconj(eR2)); cf Zb0 = cmul(zb, eAc), Zb1 = cmul(zb, eA);
        D2_W(0) D2F(0,0,0) }
      { cf zb = cmul(bw, cconj(eR));  cf Zb0 = cmul(zb, eAc), Zb1 = cmul(zb, eA);
        D2_W(1) D2F(1,0,1) D2F(1,1,0) }
      { cf zb = bw;                   cf Zb0 = cmul(zb, eAc), Zb1 = cmul(zb, eA);
        D2_W(2) D2F(2,0,2) D2F(2,1,1) D2F(2,2,0) }
      { cf zb = cmul(bw, eR);         cf Zb0 = cmul(zb, eAc), Zb1 = cmul(zb, eA);
        D2_W(3) D2F(3,1,2) D2F(3,2,1) }
      { cf zb = cmul(bw, eR2);        cf Zb0 = cmul(zb, eAc), Zb1 = cmul(zb, eA);
        D2_W(4) D2F(4,2,2) }
    }

    SCHED_WALL();

    //=========== D1_2430 (CD chain, Jr=1) ===========
    {
      const float m    = P.p[19][n];
      const float phiA = P.p[20][n];
      const float cosA = P.p[21][n];
      const float phiR = P.p[22][n];
      const float cosR = P.p[23][n];
      const float aDv  = P.p[24][n];
      const float cbD  = P.p[25][n];
      const float gDv  = P.p[26][n];

      cf g11=mkcf(gls[22],gls[23]), g12=mkcf(gls[24],gls[25]), g13=mkcf(gls[26],gls[27]),
         g14=mkcf(gls[28],gls[29]), g15=mkcf(gls[30],gls[31]);

      float q_rt = getqf(ECOMf, M0Bf, m);
      float q_nd = getqf(m, M0Cf, M0Df);
      float r2rt = rad2f(q_rt, D1_Q0RT);
      float r2nd = rad2f(q_nd, D1_Q0ND);

      float width = 0.384f * (q_nd*(1.f/D1_Q0ND)) * (2.427f/m);
      float dre = m*m - 2.427f*2.427f, dim_ = 2.427f*width;
      float inv = 1.f/(dre*dre + dim_*dim_);
      cf bw = mkcf(dre*inv, -dim_*inv);

      cf eA = epha(phiA); cf eAc = cconj(eA);
      cf eR = epha(phiR), eDa = epha(aDv), eDg = epha(gDv);

      MK_D1S(a, cosA)
      MK_D1S(r, cosR)
      MK_D1S(v, cbD)

      cf g12r = cmulr(g12, r2rt), g13r = cmulr(g13, r2rt);
      cf g15r = cmulr(g15, r2nd);

      cf F2p_0 = cmul(cadd(cmulr(g14, D1T.F2[0][0]), cmulr(g15r, D1T.F2[0][1])), PH(0,eDa));
      cf F2p_1 = cmul(cadd(cmulr(g14, D1T.F2[1][0]), cmulr(g15r, D1T.F2[1][1])), PH(1,eDa));
      cf F2p_2 = cmul(cadd(cmulr(g14, D1T.F2[2][0]), cmulr(g15r, D1T.F2[2][1])), PH(2,eDa));

      EF_LIST(MK_DDG)

      { cf zb = cmul(bw, cconj(eR)); cf Zb0 = cmul(zb, eAc), Zb1 = cmul(zb, eA);
        D1_G(0) D1F(0,0,1) D1F(0,1,0) }
      { cf zb = bw;                  cf Zb0 = cmul(zb, eAc), Zb1 = cmul(zb, eA);
        D1_G(1) D1F(1,0,2) D1F(1,1,1) D1F(1,2,0) }
      { cf zb = cmul(bw, eR);        cf Zb0 = cmul(zb, eAc), Zb1 = cmul(zb, eA);
        D1_G(2) D1F(2,1,2) D1F(2,2,1) }
    }

    EF_LIST(SUMSQ)
  }

  // wave + block reduction, one atomic per block (128 threads = 2 waves)
  #pragma unroll
  for (int off=32; off>0; off>>=1) psum += __shfl_down(psum, off, 64);
  __shared__ float red[2];
  int lane = threadIdx.x & 63, wid = threadIdx.x >> 6;
  if (lane == 0) red[wid] = psum;
  __syncthreads();
  if (threadIdx.x == 0) atomicAdd(out, red[0]+red[1]);
}

// ---------------- launch ----------------
extern "C" void kernel_launch(void* const* d_in, const int* in_sizes, int n_in,
                              void* d_out, int out_size, void* d_ws, size_t ws_size,
                              hipStream_t stream){
  (void)n_in; (void)d_ws; (void)ws_size;
  Ptrs P;
  for (int i=0; i<28; ++i) P.p[i] = (const float*)d_in[i];
  int N = in_sizes[0];
  hipMemsetAsync(d_out, 0, (size_t)out_size * sizeof(float), stream);
  int grid = (N + 127) / 128;
  amp_kernel<<<grid, 128, 0, stream>>>(P, (float*)d_out, N);
}

// Round 10
// 56.827 us; speedup vs baseline: 1.3730x; 1.2609x over previous
//
#include <hip/hip_runtime.h>
#include <math.h>

#if defined(__clang__)
#pragma float_control(precise, off)
#endif

// ---------------- compile-time coefficient generation ----------------
constexpr double cfact(int n){ double r=1.0; for (int i=2;i<=n;++i) r*=(double)i; return r; }
constexpr double csq(double x){
  if (x<=0.0) return 0.0;
  double g = x<1.0 ? 1.0 : x;
  for (int i=0;i<64;++i) g = 0.5*(g + x/g);
  return g;
}
constexpr double ccg(int j1,int j2,int m1,int m2,int j,int m){
  if (m1+m2 != m) return 0.0;
  int lo = j1-j2; if (lo<0) lo = -lo;
  if (j < lo || j > j1+j2) return 0.0;
  int am1 = m1<0?-m1:m1, am2 = m2<0?-m2:m2, am = m<0?-m:m;
  if (am1>j1 || am2>j2 || am>j) return 0.0;
  double pref = csq((2.0*j+1.0)*cfact(j+j1-j2)*cfact(j-j1+j2)*cfact(j1+j2-j)/cfact(j1+j2+j+1));
  pref = pref * csq(cfact(j+m)*cfact(j-m)*cfact(j1-m1)*cfact(j1+m1)*cfact(j2-m2)*cfact(j2+m2));
  double tot = 0.0;
  for (int k=0; k<=j1+j2-j; ++k){
    int d0=k, d1=j1+j2-j-k, d2=j1-m1-k, d3=j2+m2-k, d4=j-j2+m1+k, d5=j-j1-m2+k;
    if (d0<0||d1<0||d2<0||d3<0||d4<0||d5<0) continue;
    double p = cfact(d0)*cfact(d1)*cfact(d2)*cfact(d3)*cfact(d4)*cfact(d5);
    tot += ((k&1)? -1.0 : 1.0)/p;
  }
  return pref*tot;
}
constexpr double cq(double m, double m1, double m2){
  double ms=m1+m2, md=m1-m2;
  return csq((m+ms)*(m-ms)*(m+md)*(m-md))/(2.0*m);
}

struct ZcTab { float F1[3][2]; float F2[3][3][3]; };
constexpr ZcTab mkZcT(){
  ZcTab t{};
  const int l0l[2]={0,2}; const int l0s[2]={1,1};
  for (int ir=0; ir<3; ++ir){
    int r = ir-1;
    for (int i=0;i<2;++i){
      int l=l0l[i], s=l0s[i];
      t.F1[ir][i] = (float)( csq((2.0*l+1.0)/3.0)*ccg(1,0,r,0,s,r)*ccg(l,s,0,r,1,r) );
    }
  }
  const int l1l[3]={0,2,2}; const int l1s[3]={1,1,2};
  for (int ip=0; ip<3; ++ip) for (int iw=0; iw<3; ++iw){
    int p=ip-1, w=iw-1;
    for (int i=0;i<3;++i){
      int l=l1l[i], s=l1s[i];
      t.F2[ip][iw][i] = (float)( csq((2.0*l+1.0)/3.0)*ccg(1,1,p,-w,s,p-w)*ccg(l,s,0,p-w,1,p-w) );
    }
  }
  return t;
}
struct D2Tab { float F1[5][3][5]; float F2[3]; };
constexpr D2Tab mkD2T(){
  D2Tab t{};
  const int l0l[5]={0,2,2,2,4}; const int l0s[5]={1,1,2,3,3};
  for (int ir=0;ir<5;++ir) for (int jf=0;jf<3;++jf){
    int r=ir-2, f=jf-1;
    for (int i=0;i<5;++i){
      int l=l0l[i], s=l0s[i];
      t.F1[ir][jf][i] = (float)( csq((2.0*l+1.0)/3.0)*ccg(2,1,r,-f,s,r-f)*ccg(l,s,0,r-f,1,r-f) );
    }
  }
  for (int ip=0;ip<3;++ip){
    int p=ip-1;
    t.F2[ip] = (float)( ccg(1,0,p,0,1,p)*ccg(2,1,0,p,2,p) );
  }
  return t;
}
struct D1Tab { float F1[3][3][3]; float F2[3][2]; };
constexpr D1Tab mkD1T(){
  D1Tab t{};
  const int l0l[3]={0,2,2}; const int l0s[3]={1,1,2};
  for (int ir=0;ir<3;++ir) for (int ie=0;ie<3;++ie){
    int r=ir-1, e=ie-1;
    for (int i=0;i<3;++i){
      int l=l0l[i], s=l0s[i];
      t.F1[ir][ie][i] = (float)( csq((2.0*l+1.0)/3.0)*ccg(1,1,r,-e,s,r-e)*ccg(l,s,0,r-e,1,r-e) );
    }
  }
  const int l1l[2]={0,2}; const int l1s[2]={1,1};
  for (int iw=0;iw<3;++iw){
    int w=iw-1;
    for (int i=0;i<2;++i){
      int l=l1l[i], s=l1s[i];
      t.F2[iw][i] = (float)( csq((2.0*l+1.0)/3.0)*ccg(0,1,w,0,s,w)*ccg(l,s,0,w,1,w) );
    }
  }
  return t;
}
constexpr ZcTab ZT  = mkZcT();
constexpr D2Tab D2T = mkD2T();
constexpr D1Tab D1T = mkD1T();

constexpr double ECd=4.59925, MBd=2.01026, MCd=0.13957061, MDd=2.00685;
constexpr float ZC_Q0RT = (float)cq(ECd, MCd, 4.026);
constexpr float ZC_Q0ND = (float)cq(4.026, MBd, MCd);
constexpr float ZC_Q0BW = (float)cq(4.026, MBd, MDd);
constexpr float D2_Q0RT = (float)cq(ECd, MDd, 2.4607);
constexpr float D2_Q0ND = (float)cq(2.4607, MBd, MCd);
constexpr float D1_Q0RT = (float)cq(ECd, MBd, 2.427);
constexpr float D1_Q0ND = (float)cq(2.427, MCd, MDd);

#define ECOMf 4.59925f
#define M0Bf  2.01026f
#define M0Cf  0.13957061f
#define M0Df  2.00685f

// ---------------- complex as packed float2 (targets v_pk_*_f32 VOP3P) ----------------
typedef float cf __attribute__((ext_vector_type(2)));
__device__ __forceinline__ cf mkcf(float x, float y){ cf r; r.x = x; r.y = y; return r; }
__device__ __forceinline__ cf cadd(cf a, cf b){ return a + b; }
__device__ __forceinline__ cf cmulr(cf a, float s){ return a * s; }
__device__ __forceinline__ cf cconj(cf a){ return mkcf(a.x, -a.y); }
__device__ __forceinline__ cf cmul(cf a, cf b){
  return a.xx * b + a.yy * mkcf(-b.y, b.x);
}

__device__ __forceinline__ float hsqrt(float x){ return __builtin_amdgcn_sqrtf(x); }

__device__ __forceinline__ float getqf(float m, float m1, float m2){
  float ms = m1+m2, md = m1-m2;
  return hsqrt((m+ms)*(m-ms)*(m+md)*(m-md))/(2.f*m);
}
__device__ __forceinline__ float barrier2f(float z){ return 9.f + (3.f+z)*z; }
__device__ __forceinline__ float barrier4f(float z){ return z*(z*(z*(z+10.f)+135.f)+1575.f)+11025.f; }
__device__ __forceinline__ float rad2f(float q, float q0){
  float z = 9.f*q*q, z0 = 9.f*q0*q0;
  return q*q*hsqrt(barrier2f(z0)/barrier2f(z));
}
__device__ __forceinline__ float rad4f(float q, float q0){
  float z = 9.f*q*q, z0 = 9.f*q0*q0;
  float q2 = q*q;
  return q2*q2*hsqrt(barrier4f(z0)/barrier4f(z));
}
__device__ __forceinline__ cf epha(float a){
  const float r = a * 0.15915494309189535f;
  float c = __builtin_amdgcn_cosf(r);
  float s = __builtin_amdgcn_sinf(r);
  return mkcf(c, -s);
}

struct Ptrs { const float* p[28]; };

// VALU pinned; SALU + all VMEM may cross
#define SCHED_WALL() __builtin_amdgcn_sched_barrier(0x74)

// ---------------- macro machinery (all indices literal -> pure SSA) ----------------
#define EF_LIST(X) X(0,0) X(0,1) X(0,2) X(1,0) X(1,1) X(1,2) X(2,0) X(2,1) X(2,2)

#define PH_0(E) cconj(E)
#define PH_1(E) mkcf(1.f,0.f)
#define PH_2(E) (E)
#define PH_(M,E) PH_##M(E)
#define PH(M,E)  PH_(M,E)

#define D1_00(P) (P##A2)
#define D1_01(P) (P##AB)
#define D1_02(P) (P##B2)
#define D1_10(P) (-(P##AB))
#define D1_11(P) (P##CC)
#define D1_12(P) (P##AB)
#define D1_20(P) (P##B2)
#define D1_21(P) (-(P##AB))
#define D1_22(P) (P##A2)
#define D1E_(R,C,P) D1_##R##C(P)
#define D1E(R,C,P)  D1E_(R,C,P)

#define MK_D1S(P, CB) \
  float P##A2 = 0.5f*(1.f+(CB)); \
  float P##B2 = 0.5f*(1.f-(CB)); \
  float P##AB = 1.4142135623730951f*hsqrt(fmaxf(0.f, P##A2*P##B2)); \
  float P##CC = P##A2 - P##B2;

#define D2_0_1 (w_a3)
#define D2_0_2 (w_u6)
#define D2_0_3 (w_b3)
#define D2_1_1 (w_c1)
#define D2_1_2 (w_t6)
#define D2_1_3 (w_c2)
#define D2_2_1 (-w_t6)
#define D2_2_2 (w_c0)
#define D2_2_3 (w_t6)
#define D2_3_1 (w_c2)
#define D2_3_2 (-w_t6)
#define D2_3_3 (w_c1)
#define D2_4_1 (-w_b3)
#define D2_4_2 (w_u6)
#define D2_4_3 (-w_a3)
#define D2E_(R,C) D2_##R##_##C
#define D2E(R,C)  D2E_(R,C)

// per-event accumulators: A{ev}{a}_{e}{f}
#define DECL_A0(E,F) cf A00_##E##F = mkcf(0.f,0.f); cf A01_##E##F = mkcf(0.f,0.f);
#define DECL_A1(E,F) cf A10_##E##F = mkcf(0.f,0.f); cf A11_##E##F = mkcf(0.f,0.f);
#define SUMSQ0(E,F) psum += A00_##E##F.x*A00_##E##F.x + A00_##E##F.y*A00_##E##F.y \
                         + A01_##E##F.x*A01_##E##F.x + A01_##E##F.y*A01_##E##F.y;
#define SUMSQ1(E,F) s1 += A10_##E##F.x*A10_##E##F.x + A10_##E##F.y*A10_##E##F.y \
                        + A11_##E##F.x*A11_##E##F.x + A11_##E##F.y*A11_##E##F.y;

// ---- Zc chain ----
#define MK_DD(W,F) cf DD_##W##F = cmulr(cmul(PH(W,eDa), PH(F,eDg)), D1E(W,F,v));
#define MK_DB(P,E) cf DB_##P##E = cmulr(cmul(PH(P,eBa), PH(E,eBg)), D1E(P,E,b));
#define MK_F2(P,W) cf F2_##P##W = cadd(cmulr(g2, ZT.F2[P][W][0]), \
                      cadd(cmulr(g3r, ZT.F2[P][W][1]), cmulr(g4r, ZT.F2[P][W][2])));

#define DECL_S(E,F) cf S_##E##F = mkcf(0.f,0.f);
#define ZC_SACC_E(P,E) \
  S_##E##0 = cadd(S_##E##0, cmul(DB_##P##E, G0)); \
  S_##E##1 = cadd(S_##E##1, cmul(DB_##P##E, G1)); \
  S_##E##2 = cadd(S_##E##2, cmul(DB_##P##E, G2));
#define ZC_SACC(P) ZC_SACC_E(P,0) ZC_SACC_E(P,1) ZC_SACC_E(P,2)

#define ZC_P0(R) { \
  cf t0 = cmulr(F2_00, D1E(R,1,r)); \
  cf t1 = cmulr(F2_01, D1E(R,0,r)); \
  cf G0 = cadd(cmul(t0, DD_00), cmul(t1, DD_10)); \
  cf G1 = cadd(cmul(t0, DD_01), cmul(t1, DD_11)); \
  cf G2 = cadd(cmul(t0, DD_02), cmul(t1, DD_12)); \
  ZC_SACC(0) }
#define ZC_P1(R) { \
  cf t0 = cmulr(F2_10, D1E(R,2,r)); \
  cf t1 = cmulr(F2_11, D1E(R,1,r)); \
  cf t2 = cmulr(F2_12, D1E(R,0,r)); \
  cf G0 = cadd(cadd(cmul(t0, DD_00), cmul(t1, DD_10)), cmul(t2, DD_20)); \
  cf G1 = cadd(cadd(cmul(t0, DD_01), cmul(t1, DD_11)), cmul(t2, DD_21)); \
  cf G2 = cadd(cadd(cmul(t0, DD_02), cmul(t1, DD_12)), cmul(t2, DD_22)); \
  ZC_SACC(1) }
#define ZC_P2(R) { \
  cf t1 = cmulr(F2_21, D1E(R,2,r)); \
  cf t2 = cmulr(F2_22, D1E(R,1,r)); \
  cf G0 = cadd(cmul(t1, DD_10), cmul(t2, DD_20)); \
  cf G1 = cadd(cmul(t1, DD_11), cmul(t2, DD_21)); \
  cf G2 = cadd(cmul(t1, DD_12), cmul(t2, DD_22)); \
  ZC_SACC(2) }

#define ZC_APPLY0(E,F) \
  A00_##E##F = cadd(A00_##E##F, cmul(za0, S_##E##F)); \
  A01_##E##F = cadd(A01_##E##F, cmul(za1, S_##E##F));
#define ZC_APPLY1(E,F) \
  A10_##E##F = cadd(A10_##E##F, cmul(za0, S_##E##F)); \
  A11_##E##F = cadd(A11_##E##F, cmul(za1, S_##E##F));

#define ZC_R0(R) { \
  cf F1c = cadd(cmulr(g0, ZT.F1[R][0]), cmulr(g1r, ZT.F1[R][1])); \
  cf Zr  = cmul(F1c, PH(R,eR)); \
  cf za0 = cmulr(cmul(Zr, Ua0), D1E(0,R,a)); \
  cf za1 = cmulr(cmul(Zr, Ua1), D1E(2,R,a)); \
  EF_LIST(DECL_S) \
  ZC_P0(R) ZC_P1(R) ZC_P2(R) \
  EF_LIST(ZC_APPLY0) }
#define ZC_R1(R) { \
  cf F1c = cadd(cmulr(g0, ZT.F1[R][0]), cmulr(g1r, ZT.F1[R][1])); \
  cf Zr  = cmul(F1c, PH(R,eR)); \
  cf za0 = cmulr(cmul(Zr, Ua0), D1E(0,R,a)); \
  cf za1 = cmulr(cmul(Zr, Ua1), D1E(2,R,a)); \
  EF_LIST(DECL_S) \
  ZC_P0(R) ZC_P1(R) ZC_P2(R) \
  EF_LIST(ZC_APPLY1) }

// Zc event body (X chosen via ZC_R0/ZC_R1 at instantiation)
#define ZC_BODY(NI, ZCRM) { \
  const float m    = P.p[8][NI]; \
  const float phiA = P.p[9][NI]; \
  const float cosA = P.p[10][NI]; \
  const float phiR = P.p[11][NI]; \
  const float cosR = P.p[12][NI]; \
  const float aBv  = P.p[13][NI]; \
  const float cbB  = P.p[14][NI]; \
  const float gBv  = P.p[15][NI]; \
  const float aDv  = P.p[16][NI]; \
  const float cbD  = P.p[17][NI]; \
  const float gDv  = P.p[18][NI]; \
  float q_rt = getqf(ECOMf, M0Cf, m); \
  float q_nd = getqf(m, M0Bf, M0Df); \
  float r2rt = rad2f(q_rt, ZC_Q0RT); \
  float r2nd = rad2f(q_nd, ZC_Q0ND); \
  float width = 0.025f * (q_nd * (1.f/ZC_Q0BW)) * (4.026f / m); \
  float dre = m*m - 4.026f*4.026f, dim_ = 4.026f*width; \
  float inv = 1.f/(dre*dre + dim_*dim_); \
  cf bw = mkcf(dre*inv, -dim_*inv); \
  cf eA = epha(phiA); cf eAc = cconj(eA); \
  cf eR = epha(phiR), eBa = epha(aBv), eBg = epha(gBv), eDa = epha(aDv), eDg = epha(gDv); \
  cf Ua0 = cmul(bw, eAc); \
  cf Ua1 = cmul(bw, eA); \
  MK_D1S(a, cosA) \
  MK_D1S(r, cosR) \
  MK_D1S(b, cbB) \
  MK_D1S(v, cbD) \
  cf g1r = cmulr(g1, r2rt); \
  cf g3r = cmulr(g3, r2nd); \
  cf g4r = cmulr(g4, r2nd); \
  EF_LIST(MK_DD) \
  EF_LIST(MK_DB) \
  EF_LIST(MK_F2) \
  ZCRM(0) ZCRM(1) ZCRM(2) \
}

// ---- D2 chain ----
#define MK_DBG(P,E) cf dBg_##P##E = cmulr(PH(E,eBg), D1E(P,E,b));
#define D2_W(R) \
  cf t0 = cmulr(F2p_0, D2E(R,1)); \
  cf t1 = cmulr(F2p_1, D2E(R,2)); \
  cf t2 = cmulr(F2p_2, D2E(R,3)); \
  cf W0 = cadd(cadd(cmul(t0,dBg_00), cmul(t1,dBg_10)), cmul(t2,dBg_20)); \
  cf W1 = cadd(cadd(cmul(t0,dBg_01), cmul(t1,dBg_11)), cmul(t2,dBg_21)); \
  cf W2 = cadd(cadd(cmul(t0,dBg_02), cmul(t1,dBg_12)), cmul(t2,dBg_22));
#define D2F0(R,F,K1) { \
  cf zf = cmulr(g5, D2T.F1[R][F][0]); \
  zf = cadd(zf, cmulr(g6r, D2T.F1[R][F][1])); \
  zf = cadd(zf, cmulr(g7r, D2T.F1[R][F][2])); \
  zf = cadd(zf, cmulr(g8r, D2T.F1[R][F][3])); \
  zf = cadd(zf, cmulr(g9r, D2T.F1[R][F][4])); \
  cf z0 = cmulr(cmul(zf, Zb0), D1E(0,K1,a)); \
  cf z1 = cmulr(cmul(zf, Zb1), D1E(2,K1,a)); \
  A00_0##F = cadd(A00_0##F, cmul(z0, W0)); A01_0##F = cadd(A01_0##F, cmul(z1, W0)); \
  A00_1##F = cadd(A00_1##F, cmul(z0, W1)); A01_1##F = cadd(A01_1##F, cmul(z1, W1)); \
  A00_2##F = cadd(A00_2##F, cmul(z0, W2)); A01_2##F = cadd(A01_2##F, cmul(z1, W2)); }
#define D2F1(R,F,K1) { \
  cf zf = cmulr(g5, D2T.F1[R][F][0]); \
  zf = cadd(zf, cmulr(g6r, D2T.F1[R][F][1])); \
  zf = cadd(zf, cmulr(g7r, D2T.F1[R][F][2])); \
  zf = cadd(zf, cmulr(g8r, D2T.F1[R][F][3])); \
  zf = cadd(zf, cmulr(g9r, D2T.F1[R][F][4])); \
  cf z0 = cmulr(cmul(zf, Zb0), D1E(0,K1,a)); \
  cf z1 = cmulr(cmul(zf, Zb1), D1E(2,K1,a)); \
  A10_0##F = cadd(A10_0##F, cmul(z0, W0)); A11_0##F = cadd(A11_0##F, cmul(z1, W0)); \
  A10_1##F = cadd(A10_1##F, cmul(z0, W1)); A11_1##F = cadd(A11_1##F, cmul(z1, W1)); \
  A10_2##F = cadd(A10_2##F, cmul(z0, W2)); A11_2##F = cadd(A11_2##F, cmul(z1, W2)); }

#define D2_BODY(NI, D2FM) { \
  const float m    = P.p[0][NI]; \
  const float phiA = P.p[1][NI]; \
  const float cosA = P.p[2][NI]; \
  const float phiR = P.p[3][NI]; \
  const float cosR = P.p[4][NI]; \
  const float aBv  = P.p[5][NI]; \
  const float cbB  = P.p[6][NI]; \
  const float gBv  = P.p[7][NI]; \
  float q_rt = getqf(ECOMf, M0Df, m); \
  float q_nd = getqf(m, M0Bf, M0Cf); \
  float r2rt = rad2f(q_rt, D2_Q0RT); \
  float r4rt = rad4f(q_rt, D2_Q0RT); \
  float r2nd = rad2f(q_nd, D2_Q0ND); \
  float z = 9.f*q_nd*q_nd; \
  float bpr2 = barrier2f(9.f*D2_Q0ND*D2_Q0ND)/barrier2f(z); \
  float qr = q_nd*(1.f/D2_Q0ND); \
  float width = 0.0475f * qr*qr*qr*qr*qr * (2.4607f/m) * bpr2; \
  float dre = m*m - 2.4607f*2.4607f, dim_ = 2.4607f*width; \
  float inv = 1.f/(dre*dre + dim_*dim_); \
  cf bw = mkcf(dre*inv, -dim_*inv); \
  cf eA = epha(phiA); cf eAc = cconj(eA); \
  cf eR = epha(phiR), eBa = epha(aBv), eBg = epha(gBv); \
  cf eR2 = cmul(eR, eR); \
  MK_D1S(a, cosA) \
  MK_D1S(b, cbB) \
  float w_A2 = 0.5f*(1.f+cosR); \
  float w_B2 = 0.5f*(1.f-cosR); \
  float w_u  = w_A2*w_B2; \
  float w_AB = hsqrt(fmaxf(0.f, w_u)); \
  float w_a3 = 2.f*w_A2*w_AB, w_b3 = 2.f*w_B2*w_AB; \
  float w_t6 = 2.449489742783178f*w_AB*(w_A2-w_B2), w_u6 = 2.449489742783178f*w_u; \
  float w_c1 = w_A2*w_A2 - 3.f*w_u; \
  float w_c2 = 3.f*w_u - w_B2*w_B2; \
  float w_c0 = w_A2*w_A2 - 4.f*w_u + w_B2*w_B2; \
  cf g6r = cmulr(g6, r2rt), g7r = cmulr(g7, r2rt), g8r = cmulr(g8, r2rt); \
  cf g9r = cmulr(g9, r4rt); \
  cf g10r = cmulr(g10, r2nd); \
  cf F2p_0 = cmul(cmulr(g10r, D2T.F2[0]), PH(0,eBa)); \
  cf F2p_1 = cmul(cmulr(g10r, D2T.F2[1]), PH(1,eBa)); \
  cf F2p_2 = cmul(cmulr(g10r, D2T.F2[2]), PH(2,eBa)); \
  EF_LIST(MK_DBG) \
  { cf zb = cmul(bw, cconj(eR2)); cf Zb0 = cmul(zb, eAc), Zb1 = cmul(zb, eA); \
    D2_W(0) D2FM(0,0,0) } \
  { cf zb = cmul(bw, cconj(eR));  cf Zb0 = cmul(zb, eAc), Zb1 = cmul(zb, eA); \
    D2_W(1) D2FM(1,0,1) D2FM(1,1,0) } \
  { cf zb = bw;                   cf Zb0 = cmul(zb, eAc), Zb1 = cmul(zb, eA); \
    D2_W(2) D2FM(2,0,2) D2FM(2,1,1) D2FM(2,2,0) } \
  { cf zb = cmul(bw, eR);         cf Zb0 = cmul(zb, eAc), Zb1 = cmul(zb, eA); \
    D2_W(3) D2FM(3,1,2) D2FM(3,2,1) } \
  { cf zb = cmul(bw, eR2);        cf Zb0 = cmul(zb, eAc), Zb1 = cmul(zb, eA); \
    D2_W(4) D2FM(4,2,2) } \
}

// ---- D1 chain ----
#define MK_DDG(W,F) cf dDg_##W##F = cmulr(PH(F,eDg), D1E(W,F,v));
#define D1_G(R) \
  cf t0 = cmulr(F2p_0, D1E(R,0,r)); \
  cf t1 = cmulr(F2p_1, D1E(R,1,r)); \
  cf t2 = cmulr(F2p_2, D1E(R,2,r)); \
  cf G0 = cadd(cadd(cmul(t0,dDg_00), cmul(t1,dDg_10)), cmul(t2,dDg_20)); \
  cf G1 = cadd(cadd(cmul(t0,dDg_01), cmul(t1,dDg_11)), cmul(t2,dDg_21)); \
  cf G2 = cadd(cadd(cmul(t0,dDg_02), cmul(t1,dDg_12)), cmul(t2,dDg_22));
#define D1F0(R,E,K1) { \
  cf ze = cmulr(g11, D1T.F1[R][E][0]); \
  ze = cadd(ze, cmulr(g12r, D1T.F1[R][E][1])); \
  ze = cadd(ze, cmulr(g13r, D1T.F1[R][E][2])); \
  cf z0 = cmulr(cmul(ze, Zb0), D1E(0,K1,a)); \
  cf z1 = cmulr(cmul(ze, Zb1), D1E(2,K1,a)); \
  A00_##E##0 = cadd(A00_##E##0, cmul(z0, G0)); A01_##E##0 = cadd(A01_##E##0, cmul(z1, G0)); \
  A00_##E##1 = cadd(A00_##E##1, cmul(z0, G1)); A01_##E##1 = cadd(A01_##E##1, cmul(z1, G1)); \
  A00_##E##2 = cadd(A00_##E##2, cmul(z0, G2)); A01_##E##2 = cadd(A01_##E##2, cmul(z1, G2)); }
#define D1F1(R,E,K1) { \
  cf ze = cmulr(g11, D1T.F1[R][E][0]); \
  ze = cadd(ze, cmulr(g12r, D1T.F1[R][E][1])); \
  ze = cadd(ze, cmulr(g13r, D1T.F1[R][E][2])); \
  cf z0 = cmulr(cmul(ze, Zb0), D1E(0,K1,a)); \
  cf z1 = cmulr(cmul(ze, Zb1), D1E(2,K1,a)); \
  A10_##E##0 = cadd(A10_##E##0, cmul(z0, G0)); A11_##E##0 = cadd(A11_##E##0, cmul(z1, G0)); \
  A10_##E##1 = cadd(A10_##E##1, cmul(z0, G1)); A11_##E##1 = cadd(A11_##E##1, cmul(z1, G1)); \
  A10_##E##2 = cadd(A10_##E##2, cmul(z0, G2)); A11_##E##2 = cadd(A11_##E##2, cmul(z1, G2)); }

#define D1_BODY(NI, D1FM) { \
  const float m    = P.p[19][NI]; \
  const float phiA = P.p[20][NI]; \
  const float cosA = P.p[21][NI]; \
  const float phiR = P.p[22][NI]; \
  const float cosR = P.p[23][NI]; \
  const float aDv  = P.p[24][NI]; \
  const float cbD  = P.p[25][NI]; \
  const float gDv  = P.p[26][NI]; \
  float q_rt = getqf(ECOMf, M0Bf, m); \
  float q_nd = getqf(m, M0Cf, M0Df); \
  float r2rt = rad2f(q_rt, D1_Q0RT); \
  float r2nd = rad2f(q_nd, D1_Q0ND); \
  float width = 0.384f * (q_nd*(1.f/D1_Q0ND)) * (2.427f/m); \
  float dre = m*m - 2.427f*2.427f, dim_ = 2.427f*width; \
  float inv = 1.f/(dre*dre + dim_*dim_); \
  cf bw = mkcf(dre*inv, -dim_*inv); \
  cf eA = epha(phiA); cf eAc = cconj(eA); \
  cf eR = epha(phiR), eDa = epha(aDv), eDg = epha(gDv); \
  MK_D1S(a, cosA) \
  MK_D1S(r, cosR) \
  MK_D1S(v, cbD) \
  cf g12r = cmulr(g12, r2rt), g13r = cmulr(g13, r2rt); \
  cf g15r = cmulr(g15, r2nd); \
  cf F2p_0 = cmul(cadd(cmulr(g14, D1T.F2[0][0]), cmulr(g15r, D1T.F2[0][1])), PH(0,eDa)); \
  cf F2p_1 = cmul(cadd(cmulr(g14, D1T.F2[1][0]), cmulr(g15r, D1T.F2[1][1])), PH(1,eDa)); \
  cf F2p_2 = cmul(cadd(cmulr(g14, D1T.F2[2][0]), cmulr(g15r, D1T.F2[2][1])), PH(2,eDa)); \
  EF_LIST(MK_DDG) \
  { cf zb = cmul(bw, cconj(eR)); cf Zb0 = cmul(zb, eAc), Zb1 = cmul(zb, eA); \
    D1_G(0) D1FM(0,0,1) D1FM(0,1,0) } \
  { cf zb = bw;                  cf Zb0 = cmul(zb, eAc), Zb1 = cmul(zb, eA); \
    D1_G(1) D1FM(1,0,2) D1FM(1,1,1) D1FM(1,2,0) } \
  { cf zb = cmul(bw, eR);        cf Zb0 = cmul(zb, eAc), Zb1 = cmul(zb, eA); \
    D1_G(2) D1FM(2,1,2) D1FM(2,2,1) } \
}

// ---------------- kernel: 2 events per thread ----------------
__global__ __launch_bounds__(128, 2) void amp_kernel(Ptrs P, float* __restrict__ out, int N){
  const int tid = threadIdx.x;
  const int gid = blockIdx.x * blockDim.x + tid;
  const int half = (N + 1) >> 1;
  float psum = 0.f;
  if (gid < half) {
    const int n0 = gid;
    int n1 = gid + half;
    const float w1 = (n1 < N) ? 1.f : 0.f;
    if (n1 >= N) n1 = 0;                       // clamp (select, no branch)
    const float* __restrict__ gls = P.p[27];

    EF_LIST(DECL_A0)
    EF_LIST(DECL_A1)

    //=========== Zc_4025 (both events, one region) ===========
    {
      cf g0=mkcf(gls[0],gls[1]), g1=mkcf(gls[2],gls[3]), g2=mkcf(gls[4],gls[5]),
         g3=mkcf(gls[6],gls[7]), g4=mkcf(gls[8],gls[9]);
      ZC_BODY(n0, ZC_R0)
      ZC_BODY(n1, ZC_R1)
    }

    SCHED_WALL();

    //=========== D2_2460 (both events, one region) ===========
    {
      cf g5=mkcf(gls[10],gls[11]), g6=mkcf(gls[12],gls[13]), g7=mkcf(gls[14],gls[15]),
         g8=mkcf(gls[16],gls[17]), g9=mkcf(gls[18],gls[19]), g10=mkcf(gls[20],gls[21]);
      D2_BODY(n0, D2F0)
      D2_BODY(n1, D2F1)
    }

    SCHED_WALL();

    //=========== D1_2430 (both events, one region) ===========
    {
      cf g11=mkcf(gls[22],gls[23]), g12=mkcf(gls[24],gls[25]), g13=mkcf(gls[26],gls[27]),
         g14=mkcf(gls[28],gls[29]), g15=mkcf(gls[30],gls[31]);
      D1_BODY(n0, D1F0)
      D1_BODY(n1, D1F1)
    }

    EF_LIST(SUMSQ0)
    float s1 = 0.f;
    EF_LIST(SUMSQ1)
    psum += w1 * s1;
  }

  // wave + block reduction, one atomic per block (128 threads = 2 waves)
  #pragma unroll
  for (int off=32; off>0; off>>=1) psum += __shfl_down(psum, off, 64);
  __shared__ float red[2];
  int lane = threadIdx.x & 63, wid = threadIdx.x >> 6;
  if (lane == 0) red[wid] = psum;
  __syncthreads();
  if (threadIdx.x == 0) atomicAdd(out, red[0]+red[1]);
}

// ---------------- launch ----------------
extern "C" void kernel_launch(void* const* d_in, const int* in_sizes, int n_in,
                              void* d_out, int out_size, void* d_ws, size_t ws_size,
                              hipStream_t stream){
  (void)n_in; (void)d_ws; (void)ws_size;
  Ptrs P;
  for (int i=0; i<28; ++i) P.p[i] = (const float*)d_in[i];
  int N = in_sizes[0];
  hipMemsetAsync(d_out, 0, (size_t)out_size * sizeof(float), stream);
  int half = (N + 1) >> 1;
  int grid = (half + 127) / 128;
  amp_kernel<<<grid, 128, 0, stream>>>(P, (float*)d_out, N);
}